// Round 8
// baseline (501.192 us; speedup 1.0000x reference)
//
#include <hip/hip_runtime.h>

// ---------------------------------------------------------------------------
// GLMAttention: qkv proj (+RoPE) -> fused flash attn (scores out + softmax+PV)
// -> output proj.  All matmuls fp16 MFMA (16x16x32), f32 accumulate.
// B=4 S=1024 HID=2048 H=16 D=128.
// Round 8: flash BT 64->32. LDS 72KB->37KB -> 4 blocks/CU (16 waves/CU,
// grid 1024 = exactly 4/CU, no tail). Same 2-phase double-buffered schedule.
// V swizzle ((vr>>1)&3)<<3 (2-way, free); P buffer padded to 40 elems/row
// (ds_write-staged, padding legal) -> conflict-free, no XOR.
// ---------------------------------------------------------------------------

#define B_  4
#define S_  1024
#define HID_ 2048
#define H_  16
#define D_  128
#define RSQRT_D 0.08838834764831845f

typedef _Float16 f16x8 __attribute__((ext_vector_type(8)));
typedef _Float16 f16x4 __attribute__((ext_vector_type(4)));
typedef float f32x4 __attribute__((ext_vector_type(4)));

#define MFMA16(a, b, c) __builtin_amdgcn_mfma_f32_16x16x32_f16(a, b, c, 0, 0, 0)

__device__ __forceinline__ void gll16(const void* g, void* l) {
  __builtin_amdgcn_global_load_lds(
      (const __attribute__((address_space(1))) void*)g,
      (__attribute__((address_space(3))) void*)l, 16, 0, 0);
}

// ---------------------------------------------------------------------------
// RoPE tables: cos/sin[pos][j], j in [0,32), inv_freq = 10000^(-j/32)
// ---------------------------------------------------------------------------
__global__ void rope_table_kernel(float* __restrict__ tcos, float* __restrict__ tsin) {
  int i = blockIdx.x * blockDim.x + threadIdx.x;  // 32768 = 1024*32
  int pos = i >> 5, j = i & 31;
  float inv = expf(-(float)j * (9.210340371976184f / 32.0f));  // ln(10000)/32
  float ang = (float)pos * inv;
  tcos[i] = cosf(ang);
  tsin[i] = sinf(ang);
}

// ---------------------------------------------------------------------------
// f32 -> f16 convert, 8 elems/thread, vectorized
// ---------------------------------------------------------------------------
__global__ void cvt_kernel(const float* __restrict__ in, _Float16* __restrict__ out, int n8) {
  int i = blockIdx.x * blockDim.x + threadIdx.x;
  if (i >= n8) return;
  const f32x4* in4 = (const f32x4*)in;
  f32x4 a = in4[i * 2], b = in4[i * 2 + 1];
  f16x8 v;
  v[0] = (_Float16)a[0]; v[1] = (_Float16)a[1]; v[2] = (_Float16)a[2]; v[3] = (_Float16)a[3];
  v[4] = (_Float16)b[0]; v[5] = (_Float16)b[1]; v[6] = (_Float16)b[2]; v[7] = (_Float16)b[3];
  *(f16x8*)(out + (size_t)i * 8) = v;
}

// ---------------------------------------------------------------------------
// GEMM: C = A(MxK) @ W(NxK)^T + bias.  128x128 tile, BK=64, 4 waves, 4x4 frags.
// MODE 0: RoPE epilogue  -> f16 out (B,H,S,D)
// MODE 1: V head, transposed -> f16 out (B,H,D,S)
// MODE 2: f32 + bias     -> f32 out (M,N)  (final output)
// ---------------------------------------------------------------------------
template <int MODE>
__global__ __launch_bounds__(256) void proj_kernel(
    const _Float16* __restrict__ A, const _Float16* __restrict__ Bw,
    const float* __restrict__ bias, void* __restrict__ outp,
    const int* __restrict__ pids, const float* __restrict__ tcos,
    const float* __restrict__ tsin) {
  constexpr int N = HID_, K = HID_;
  constexpr int BK = 64;
  __shared__ _Float16 As[128 * BK];
  __shared__ _Float16 Bs[128 * BK];

  const int tid = threadIdx.x;
  // XCD-aware swizzle (512 blocks, 512%8==0 -> bijective)
  const int bid = (blockIdx.x & 7) * 64 + (blockIdx.x >> 3);
  const int tm = bid >> 4, tn = bid & 15;  // 32 x 16 tiles
  const int m0 = tm * 128, n0 = tn * 128;
  const int w = tid >> 6, l = tid & 63;
  const int mw = (w >> 1) * 64, nw = (w & 1) * 64;
  const int lr = l & 15, lh = l >> 4;

  f32x4 acc[4][4] = {};

  for (int kt = 0; kt < K / BK; ++kt) {
    const int k0 = kt * BK;
    __syncthreads();
#pragma unroll
    for (int i = 0; i < 4; ++i) {
      const int e = i * 2048 + tid * 8;
      gll16(A + (size_t)(m0 + (e >> 6)) * K + k0 + (e & 63), As + e);
      gll16(Bw + (size_t)(n0 + (e >> 6)) * K + k0 + (e & 63), Bs + e);
    }
    asm volatile("s_waitcnt vmcnt(0)" ::: "memory");
    __syncthreads();
#pragma unroll
    for (int kk = 0; kk < 2; ++kk) {
      f16x8 af[4], bf[4];
#pragma unroll
      for (int mi = 0; mi < 4; ++mi)
        af[mi] = *(const f16x8*)(As + (mw + mi * 16 + lr) * BK + kk * 32 + lh * 8);
#pragma unroll
      for (int ni = 0; ni < 4; ++ni)
        bf[ni] = *(const f16x8*)(Bs + (nw + ni * 16 + lr) * BK + kk * 32 + lh * 8);
#pragma unroll
      for (int mi = 0; mi < 4; ++mi)
#pragma unroll
        for (int ni = 0; ni < 4; ++ni)
          acc[mi][ni] = MFMA16(af[mi], bf[ni], acc[mi][ni]);
    }
  }

  if constexpr (MODE == 2) {
    float* out = (float*)outp;
#pragma unroll
    for (int mi = 0; mi < 4; ++mi)
#pragma unroll
      for (int ni = 0; ni < 4; ++ni) {
        const int col = n0 + nw + ni * 16 + lr;
        const float bb = bias[col];
#pragma unroll
        for (int r = 0; r < 4; ++r) {
          const int row = m0 + mw + mi * 16 + lh * 4 + r;
          out[(size_t)row * N + col] = acc[mi][ni][r] + bb;
        }
      }
  } else if constexpr (MODE == 1) {  // V: write (B,H,D,S) directly
    _Float16* out = (_Float16*)outp;
#pragma unroll
    for (int mi = 0; mi < 4; ++mi)
#pragma unroll
      for (int ni = 0; ni < 4; ++ni) {
        const int col = n0 + nw + ni * 16 + lr;
        const float bb = bias[col];
        const int h = col >> 7, hd = col & 127;
#pragma unroll
        for (int r = 0; r < 4; ++r) {
          const int row = m0 + mw + mi * 16 + lh * 4 + r;
          const int b = row >> 10, s = row & 1023;
          out[(((size_t)(b * H_ + h)) * D_ + hd) * S_ + s] = (_Float16)(acc[mi][ni][r] + bb);
        }
      }
  } else {  // MODE 0: RoPE. wave covers cols [c0,c0+64) = head dims [0,64) or [64,128)
    _Float16* out = (_Float16*)outp;
    const int sel = (nw >> 6) & 1;  // 0 -> pid row, 1 -> bid row of position_ids
#pragma unroll
    for (int mi = 0; mi < 4; ++mi) {
#pragma unroll
      for (int r = 0; r < 4; ++r) {
        const int row = m0 + mw + mi * 16 + lh * 4 + r;
        const int b = row >> 10, s = row & 1023;
        const int pos = pids[b * 2 * S_ + sel * S_ + s];
#pragma unroll
        for (int ni = 0; ni < 2; ++ni) {
          const int col = n0 + nw + ni * 16 + lr;  // first of (d, d+32) pair
          const int j = ni * 16 + lr;              // 0..31 freq index
          const float c = tcos[pos * 32 + j];
          const float sn = tsin[pos * 32 + j];
          const float x1 = acc[mi][ni][r] + bias[col];
          const float x2 = acc[mi][ni + 2][r] + bias[col + 32];
          const int h = col >> 7, hd = col & 127;
          const size_t base = (((size_t)(b * H_ + h)) * S_ + s) * D_;
          out[base + hd] = (_Float16)(x1 * c - x2 * sn);
          out[base + hd + 32] = (_Float16)(x2 * c + x1 * sn);
        }
      }
    }
  }
}

// ---------------------------------------------------------------------------
// Fused flash attention, 2-phase double-buffered, BT=32.
// Block = (b,h, 64 q-rows); 4 waves x 16 rows. Swapped MFMA operands
// (S layout [t][q], o layout [d][q]). Per iteration: issue streams(t),
// STAGE(t+1) into other buffer, compute(t), __syncthreads (sole drain), swap.
// LDS 37KB -> 4 blocks/CU.
// ---------------------------------------------------------------------------
__global__ __launch_bounds__(256) void flash_kernel(
    const _Float16* __restrict__ q, const _Float16* __restrict__ k,
    const _Float16* __restrict__ vt, const float* __restrict__ pbias,
    const float* __restrict__ maskp, const float* __restrict__ prev,
    float* __restrict__ scores, _Float16* __restrict__ ctx) {
  constexpr int BT = 32;
  constexpr int PLD = 40;                    // padded P row (conflict-free)
  __shared__ _Float16 KsBuf[2][BT * D_];     // [t][d] swizzled, 2 x 8 KB
  __shared__ _Float16 VTsBuf[2][D_ * BT];    // [d][t] swizzled, 2 x 8 KB
  __shared__ _Float16 Ps[4][16 * PLD];       // per-wave [q][t] padded, 5 KB

  const int tid = threadIdx.x, w = tid >> 6, l = tid & 63;
  const int lr = l & 15, lh = l >> 4;
  // XCD swizzle: 1024 blocks -> 128 consecutive per XCD (8 planes/XCD)
  const int sid = (blockIdx.x & 7) * 128 + (blockIdx.x >> 3);
  const int qt = sid & 15, byh = sid >> 4;
  const int b = byh >> 4, h = byh & 15;
  const size_t plane = (size_t)byh;
  const int q0 = qt * 64 + w * 16;
  const int qrow = q0 + lr;           // this lane's q-row
  const int swzK = (lr & 7) << 3;     // K frag-read XOR (row=...+lr)

  const float* prow  = prev  + (plane * S_ + qrow) * S_;
  const float* pbrow = pbias + ((size_t)h * S_ + qrow) * S_;
  const float* mrow  = maskp + ((size_t)b * S_ + qrow) * S_;
  float*       srow  = scores + (plane * S_ + qrow) * S_;
  const _Float16* kpl = k  + plane * S_ * D_;
  const _Float16* vpl = vt + plane * D_ * S_;

  // Q B-fragments: lane provides Q[row=lr][k]
  f16x8 qa[4];
#pragma unroll
  for (int kk = 0; kk < 4; ++kk)
    qa[kk] = *(const f16x8*)(q + (plane * S_ + qrow) * D_ + kk * 32 + lh * 8);

  f32x4 o[8] = {};
  float m_r = -1e30f, l_r = 0.0f;

  _Float16* ksA = &KsBuf[0][0];
  _Float16* ksB = &KsBuf[1][0];
  _Float16* vtA = &VTsBuf[0][0];
  _Float16* vtB = &VTsBuf[1][0];

  // prologue: stage tile 0 into buffer A (pre-swizzled sources)
#pragma unroll
  for (int i = 0; i < 2; ++i) {
    const int e = i * 2048 + tid * 8;
    const int krow = e >> 7;
    gll16(kpl + (size_t)krow * D_ + ((e & 127) ^ ((krow & 7) << 3)), ksA + e);
    const int vrow = e >> 5;
    gll16(vpl + (size_t)vrow * S_ + ((e & 31) ^ (((vrow >> 1) & 3) << 3)), vtA + e);
  }
  __syncthreads();   // compiler drains vmcnt before s_barrier

  for (int tt = 0; tt < S_ / BT; ++tt) {
    const int t0 = tt * BT;

    // streams for THIS tile (needed after QK^T; deepest-issued)
    f32x4 pv4[2], pb4[2], mk4[2];
#pragma unroll
    for (int nt = 0; nt < 2; ++nt) {
      const int toff = t0 + nt * 16 + lh * 4;
      pv4[nt] = __builtin_nontemporal_load((const f32x4*)(prow + toff));
      pb4[nt] = *(const f32x4*)(pbrow + toff);
      mk4[nt] = *(const f32x4*)(mrow + toff);
    }
    // STAGE next tile into the other buffer (async DMA, drained at the
    // end-of-iteration barrier after the whole compute phase)
    if (tt < S_ / BT - 1) {
      const int t1 = t0 + BT;
#pragma unroll
      for (int i = 0; i < 2; ++i) {
        const int e = i * 2048 + tid * 8;
        const int krow = e >> 7;
        gll16(kpl + (size_t)(t1 + krow) * D_ + ((e & 127) ^ ((krow & 7) << 3)), ksB + e);
        const int vrow = e >> 5;
        gll16(vpl + (size_t)vrow * S_ + t1 + ((e & 31) ^ (((vrow >> 1) & 3) << 3)), vtB + e);
      }
    }

    // QK^T swapped: sa[nt][r] = S[t = t0+nt*16+lh*4+r][q = qrow]
    f32x4 sa[2] = {};
    __builtin_amdgcn_s_setprio(1);
#pragma unroll
    for (int nt = 0; nt < 2; ++nt)
#pragma unroll
      for (int kk = 0; kk < 4; ++kk) {
        const int row = nt * 16 + lr;
        f16x8 kb = *(const f16x8*)(ksA + row * D_ + ((kk * 32 + lh * 8) ^ swzK));
        sa[nt] = MFMA16(kb, qa[kk], sa[nt]);
      }
    __builtin_amdgcn_s_setprio(0);

    // epilogue: score = (qk+pb)/sqrtD + mask + prev ; pure VALU + store
#pragma unroll
    for (int nt = 0; nt < 2; ++nt) {
      const int toff = t0 + nt * 16 + lh * 4;
      f32x4 sc4 = (sa[nt] + pb4[nt]) * RSQRT_D + mk4[nt] + pv4[nt];
      __builtin_nontemporal_store(sc4, (f32x4*)(srow + toff));
      sa[nt] = sc4;
    }

    // online softmax, one q-row per lane; row group = lanes {l, l^16, l^32, l^48}
    float tmx = fmaxf(fmaxf(fmaxf(sa[0][0], sa[0][1]), fmaxf(sa[0][2], sa[0][3])),
                      fmaxf(fmaxf(sa[1][0], sa[1][1]), fmaxf(sa[1][2], sa[1][3])));
    tmx = fmaxf(tmx, __shfl_xor(tmx, 16));
    tmx = fmaxf(tmx, __shfl_xor(tmx, 32));
    if (!__all(tmx <= m_r + 8.0f)) {   // T13 defer-max
      const float newm = fmaxf(m_r, tmx);
      const float al = __expf(m_r - newm);
      m_r = newm;
      l_r *= al;
#pragma unroll
      for (int nd = 0; nd < 8; ++nd) o[nd] *= al;
    }
    float ts = 0.0f;
#pragma unroll
    for (int nt = 0; nt < 2; ++nt)
#pragma unroll
      for (int r = 0; r < 4; ++r) {
        const float pe = __expf(sa[nt][r] - m_r);
        sa[nt][r] = pe;
        ts += pe;
      }
    ts += __shfl_xor(ts, 16);
    ts += __shfl_xor(ts, 32);
    l_r += ts;

    // P -> per-wave LDS [q=lr][t], padded row (no XOR), f16x4 stores
    _Float16* pw = &Ps[w][0];
#pragma unroll
    for (int nt = 0; nt < 2; ++nt) {
      f16x4 pk;
      pk[0] = (_Float16)sa[nt][0]; pk[1] = (_Float16)sa[nt][1];
      pk[2] = (_Float16)sa[nt][2]; pk[3] = (_Float16)sa[nt][3];
      *(f16x4*)(pw + lr * PLD + nt * 16 + lh * 4) = pk;
    }

    // PV swapped: o[nd][r] = ctx[d = nd*16+lh*4+r][q = qrow]; K-dim = BT = 32
    const f16x8 pa = *(const f16x8*)(pw + lr * PLD + lh * 8);
    __builtin_amdgcn_s_setprio(1);
#pragma unroll
    for (int nd = 0; nd < 8; ++nd) {
      const int vr = nd * 16 + lr;
      const f16x8 vb = *(const f16x8*)(vtA + vr * BT + ((lh * 8) ^ (((vr >> 1) & 3) << 3)));
      o[nd] = MFMA16(vb, pa, o[nd]);
    }
    __builtin_amdgcn_s_setprio(0);

    // sole drain point: waits this wave's gll16s + ds ops, then barrier
    __syncthreads();
    _Float16* t1p = ksA; ksA = ksB; ksB = t1p;
    _Float16* t2p = vtA; vtA = vtB; vtB = t2p;
  }

  // ctx write: lane owns q-row qrow, d = nd*16 + lh*4 + r -> f16x4 stores
  const float inv_l = 1.0f / l_r;
  _Float16* crow = ctx + ((size_t)(b * S_) + qrow) * HID_ + h * D_;
#pragma unroll
  for (int nd = 0; nd < 8; ++nd) {
    f16x4 cv;
#pragma unroll
    for (int r = 0; r < 4; ++r) cv[r] = (_Float16)(o[nd][r] * inv_l);
    *(f16x4*)(crow + nd * 16 + lh * 4) = cv;
  }
}

// ---------------------------------------------------------------------------
extern "C" void kernel_launch(void* const* d_in, const int* in_sizes, int n_in,
                              void* d_out, int out_size, void* d_ws, size_t ws_size,
                              hipStream_t stream) {
  const float* query = (const float*)d_in[0];
  const float* key_i = (const float*)d_in[1];
  const float* value = (const float*)d_in[2];
  const float* maskp = (const float*)d_in[3];
  const float* pbias = (const float*)d_in[4];
  const float* prev  = (const float*)d_in[5];
  const int*   pids  = (const int*)d_in[6];
  const float* Wq = (const float*)d_in[7];
  const float* bq = (const float*)d_in[8];
  const float* Wk = (const float*)d_in[9];
  const float* bk = (const float*)d_in[10];
  const float* Wv = (const float*)d_in[11];
  const float* bv = (const float*)d_in[12];
  const float* Wo = (const float*)d_in[13];
  const float* bo = (const float*)d_in[14];

  char* ws = (char*)d_ws;
  // workspace layout (bytes); total need = 134,479,872
  const size_t OFF_TCOS = 0;
  const size_t OFF_TSIN = 131072;
  const size_t OFF_W    = 262144;                      // 4 x 8 MB f16 weights
  const size_t OFF_X    = OFF_W + 4ull * 8388608;      // 3 x 16 MB f16 X
  const size_t OFF_Q    = OFF_X + 3ull * 16777216;
  const size_t OFF_K    = OFF_Q + 16777216;
  const size_t OFF_VT   = OFF_K + 16777216;            // V proj writes here (B,H,D,S)
  const size_t OFF_CTX  = OFF_X + 16777216;            // reuse Xk (consumed)

  float* tcos = (float*)(ws + OFF_TCOS);
  float* tsin = (float*)(ws + OFF_TSIN);
  _Float16* Wq16 = (_Float16*)(ws + OFF_W);
  _Float16* Wk16 = (_Float16*)(ws + OFF_W + 8388608);
  _Float16* Wv16 = (_Float16*)(ws + OFF_W + 2ull * 8388608);
  _Float16* Wo16 = (_Float16*)(ws + OFF_W + 3ull * 8388608);
  _Float16* Xq16 = (_Float16*)(ws + OFF_X);
  _Float16* Xk16 = (_Float16*)(ws + OFF_X + 16777216);
  _Float16* Xv16 = (_Float16*)(ws + OFF_X + 2ull * 16777216);
  _Float16* q16  = (_Float16*)(ws + OFF_Q);
  _Float16* k16  = (_Float16*)(ws + OFF_K);
  _Float16* vt16 = (_Float16*)(ws + OFF_VT);
  _Float16* ctx16 = (_Float16*)(ws + OFF_CTX);

  float* out_f32 = (float*)d_out;                 // (B,S,HID) = 8,388,608
  float* scores  = (float*)d_out + 8388608;       // (B,H,S,S) = 67,108,864

  rope_table_kernel<<<128, 256, 0, stream>>>(tcos, tsin);

  cvt_kernel<<<2048, 256, 0, stream>>>(Wq, Wq16, 524288);
  cvt_kernel<<<2048, 256, 0, stream>>>(Wk, Wk16, 524288);
  cvt_kernel<<<2048, 256, 0, stream>>>(Wv, Wv16, 524288);
  cvt_kernel<<<2048, 256, 0, stream>>>(Wo, Wo16, 524288);
  cvt_kernel<<<4096, 256, 0, stream>>>(query, Xq16, 1048576);
  cvt_kernel<<<4096, 256, 0, stream>>>(key_i, Xk16, 1048576);
  cvt_kernel<<<4096, 256, 0, stream>>>(value, Xv16, 1048576);

  proj_kernel<0><<<512, 256, 0, stream>>>(Xq16, Wq16, bq, (void*)q16, pids, tcos, tsin);
  proj_kernel<0><<<512, 256, 0, stream>>>(Xk16, Wk16, bk, (void*)k16, pids, tcos, tsin);
  proj_kernel<1><<<512, 256, 0, stream>>>(Xv16, Wv16, bv, (void*)vt16, nullptr, nullptr, nullptr);

  flash_kernel<<<1024, 256, 0, stream>>>(q16, k16, vt16, pbias, maskp, prev,
                                         scores, ctx16);

  proj_kernel<2><<<512, 256, 0, stream>>>(ctx16, Wo16, bo, (void*)out_f32,
                                          nullptr, nullptr, nullptr);
}

// Round 9
// 488.902 us; speedup vs baseline: 1.0251x; 1.0251x over previous
//
#include <hip/hip_runtime.h>

// ---------------------------------------------------------------------------
// GLMAttention: qkv proj (+RoPE) -> fused flash attn (scores out + softmax+PV)
// -> output proj.  All matmuls fp16 MFMA (16x16x32), f32 accumulate.
// B=4 S=1024 HID=2048 H=16 D=128.
// Round 9: flash back to BT=64 2-phase dbuf (round-7 schedule), but 512-thread
// blocks: 8 waves share one K/V double-buffer -> 16 waves/CU (was 8) at the
// same LDS cost per wave. Grid 512 = exactly 2 blocks/CU.
// ---------------------------------------------------------------------------

#define B_  4
#define S_  1024
#define HID_ 2048
#define H_  16
#define D_  128
#define RSQRT_D 0.08838834764831845f

typedef _Float16 f16x8 __attribute__((ext_vector_type(8)));
typedef _Float16 f16x4 __attribute__((ext_vector_type(4)));
typedef float f32x4 __attribute__((ext_vector_type(4)));

#define MFMA16(a, b, c) __builtin_amdgcn_mfma_f32_16x16x32_f16(a, b, c, 0, 0, 0)

__device__ __forceinline__ void gll16(const void* g, void* l) {
  __builtin_amdgcn_global_load_lds(
      (const __attribute__((address_space(1))) void*)g,
      (__attribute__((address_space(3))) void*)l, 16, 0, 0);
}

// ---------------------------------------------------------------------------
// RoPE tables: cos/sin[pos][j], j in [0,32), inv_freq = 10000^(-j/32)
// ---------------------------------------------------------------------------
__global__ void rope_table_kernel(float* __restrict__ tcos, float* __restrict__ tsin) {
  int i = blockIdx.x * blockDim.x + threadIdx.x;  // 32768 = 1024*32
  int pos = i >> 5, j = i & 31;
  float inv = expf(-(float)j * (9.210340371976184f / 32.0f));  // ln(10000)/32
  float ang = (float)pos * inv;
  tcos[i] = cosf(ang);
  tsin[i] = sinf(ang);
}

// ---------------------------------------------------------------------------
// f32 -> f16 convert, 8 elems/thread, vectorized
// ---------------------------------------------------------------------------
__global__ void cvt_kernel(const float* __restrict__ in, _Float16* __restrict__ out, int n8) {
  int i = blockIdx.x * blockDim.x + threadIdx.x;
  if (i >= n8) return;
  const f32x4* in4 = (const f32x4*)in;
  f32x4 a = in4[i * 2], b = in4[i * 2 + 1];
  f16x8 v;
  v[0] = (_Float16)a[0]; v[1] = (_Float16)a[1]; v[2] = (_Float16)a[2]; v[3] = (_Float16)a[3];
  v[4] = (_Float16)b[0]; v[5] = (_Float16)b[1]; v[6] = (_Float16)b[2]; v[7] = (_Float16)b[3];
  *(f16x8*)(out + (size_t)i * 8) = v;
}

// ---------------------------------------------------------------------------
// GEMM: C = A(MxK) @ W(NxK)^T + bias.  128x128 tile, BK=64, 4 waves, 4x4 frags.
// MODE 0: RoPE epilogue  -> f16 out (B,H,S,D)
// MODE 1: V head, transposed -> f16 out (B,H,D,S)
// MODE 2: f32 + bias     -> f32 out (M,N)  (final output)
// ---------------------------------------------------------------------------
template <int MODE>
__global__ __launch_bounds__(256) void proj_kernel(
    const _Float16* __restrict__ A, const _Float16* __restrict__ Bw,
    const float* __restrict__ bias, void* __restrict__ outp,
    const int* __restrict__ pids, const float* __restrict__ tcos,
    const float* __restrict__ tsin) {
  constexpr int N = HID_, K = HID_;
  constexpr int BK = 64;
  __shared__ _Float16 As[128 * BK];
  __shared__ _Float16 Bs[128 * BK];

  const int tid = threadIdx.x;
  // XCD-aware swizzle (512 blocks, 512%8==0 -> bijective)
  const int bid = (blockIdx.x & 7) * 64 + (blockIdx.x >> 3);
  const int tm = bid >> 4, tn = bid & 15;  // 32 x 16 tiles
  const int m0 = tm * 128, n0 = tn * 128;
  const int w = tid >> 6, l = tid & 63;
  const int mw = (w >> 1) * 64, nw = (w & 1) * 64;
  const int lr = l & 15, lh = l >> 4;

  f32x4 acc[4][4] = {};

  for (int kt = 0; kt < K / BK; ++kt) {
    const int k0 = kt * BK;
    __syncthreads();
#pragma unroll
    for (int i = 0; i < 4; ++i) {
      const int e = i * 2048 + tid * 8;
      gll16(A + (size_t)(m0 + (e >> 6)) * K + k0 + (e & 63), As + e);
      gll16(Bw + (size_t)(n0 + (e >> 6)) * K + k0 + (e & 63), Bs + e);
    }
    asm volatile("s_waitcnt vmcnt(0)" ::: "memory");
    __syncthreads();
#pragma unroll
    for (int kk = 0; kk < 2; ++kk) {
      f16x8 af[4], bf[4];
#pragma unroll
      for (int mi = 0; mi < 4; ++mi)
        af[mi] = *(const f16x8*)(As + (mw + mi * 16 + lr) * BK + kk * 32 + lh * 8);
#pragma unroll
      for (int ni = 0; ni < 4; ++ni)
        bf[ni] = *(const f16x8*)(Bs + (nw + ni * 16 + lr) * BK + kk * 32 + lh * 8);
#pragma unroll
      for (int mi = 0; mi < 4; ++mi)
#pragma unroll
        for (int ni = 0; ni < 4; ++ni)
          acc[mi][ni] = MFMA16(af[mi], bf[ni], acc[mi][ni]);
    }
  }

  if constexpr (MODE == 2) {
    float* out = (float*)outp;
#pragma unroll
    for (int mi = 0; mi < 4; ++mi)
#pragma unroll
      for (int ni = 0; ni < 4; ++ni) {
        const int col = n0 + nw + ni * 16 + lr;
        const float bb = bias[col];
#pragma unroll
        for (int r = 0; r < 4; ++r) {
          const int row = m0 + mw + mi * 16 + lh * 4 + r;
          out[(size_t)row * N + col] = acc[mi][ni][r] + bb;
        }
      }
  } else if constexpr (MODE == 1) {  // V: write (B,H,D,S) directly
    _Float16* out = (_Float16*)outp;
#pragma unroll
    for (int mi = 0; mi < 4; ++mi)
#pragma unroll
      for (int ni = 0; ni < 4; ++ni) {
        const int col = n0 + nw + ni * 16 + lr;
        const float bb = bias[col];
        const int h = col >> 7, hd = col & 127;
#pragma unroll
        for (int r = 0; r < 4; ++r) {
          const int row = m0 + mw + mi * 16 + lh * 4 + r;
          const int b = row >> 10, s = row & 1023;
          out[(((size_t)(b * H_ + h)) * D_ + hd) * S_ + s] = (_Float16)(acc[mi][ni][r] + bb);
        }
      }
  } else {  // MODE 0: RoPE. wave covers cols [c0,c0+64) = head dims [0,64) or [64,128)
    _Float16* out = (_Float16*)outp;
    const int sel = (nw >> 6) & 1;  // 0 -> pid row, 1 -> bid row of position_ids
#pragma unroll
    for (int mi = 0; mi < 4; ++mi) {
#pragma unroll
      for (int r = 0; r < 4; ++r) {
        const int row = m0 + mw + mi * 16 + lh * 4 + r;
        const int b = row >> 10, s = row & 1023;
        const int pos = pids[b * 2 * S_ + sel * S_ + s];
#pragma unroll
        for (int ni = 0; ni < 2; ++ni) {
          const int col = n0 + nw + ni * 16 + lr;  // first of (d, d+32) pair
          const int j = ni * 16 + lr;              // 0..31 freq index
          const float c = tcos[pos * 32 + j];
          const float sn = tsin[pos * 32 + j];
          const float x1 = acc[mi][ni][r] + bias[col];
          const float x2 = acc[mi][ni + 2][r] + bias[col + 32];
          const int h = col >> 7, hd = col & 127;
          const size_t base = (((size_t)(b * H_ + h)) * S_ + s) * D_;
          out[base + hd] = (_Float16)(x1 * c - x2 * sn);
          out[base + hd + 32] = (_Float16)(x2 * c + x1 * sn);
        }
      }
    }
  }
}

// ---------------------------------------------------------------------------
// Fused flash attention, 2-phase double-buffered, BT=64, 8 waves/block.
// Block = (b,h, 128 q-rows); 8 waves x 16 rows share one K/V double-buffer.
// Swapped MFMA operands (S layout [t][q], o layout [d][q]); LDS XOR-swizzled
// via pre-swizzled global_load_lds source. Per iteration: issue streams(t),
// STAGE(t+1) into other buffer, compute(t), __syncthreads (sole drain), swap.
// LDS 80KB -> 2 blocks/CU = 16 waves/CU.
// ---------------------------------------------------------------------------
__global__ __launch_bounds__(512) void flash_kernel(
    const _Float16* __restrict__ q, const _Float16* __restrict__ k,
    const _Float16* __restrict__ vt, const float* __restrict__ pbias,
    const float* __restrict__ maskp, const float* __restrict__ prev,
    float* __restrict__ scores, _Float16* __restrict__ ctx) {
  constexpr int BT = 64;
  __shared__ _Float16 KsBuf[2][BT * D_];   // [t][d] swizzled, 2 x 16 KB
  __shared__ _Float16 VTsBuf[2][D_ * BT];  // [d][t] swizzled, 2 x 16 KB
  __shared__ _Float16 Ps[8][16 * BT];      // per-wave [q][t] swizzled, 16 KB

  const int tid = threadIdx.x, w = tid >> 6, l = tid & 63;
  const int lr = l & 15, lh = l >> 4;
  // XCD swizzle: 512 blocks -> 64 consecutive per XCD (8 planes/XCD)
  const int sid = (blockIdx.x & 7) * 64 + (blockIdx.x >> 3);
  const int qt = sid & 7, byh = sid >> 3;
  const int b = byh >> 4, h = byh & 15;
  const size_t plane = (size_t)byh;
  const int q0 = qt * 128 + w * 16;   // 8 waves x 16 rows = 128 rows/block
  const int qrow = q0 + lr;           // this lane's q-row
  const int swz = (lr & 7) << 3;      // element-index XOR for frag reads

  const float* prow  = prev  + (plane * S_ + qrow) * S_;
  const float* pbrow = pbias + ((size_t)h * S_ + qrow) * S_;
  const float* mrow  = maskp + ((size_t)b * S_ + qrow) * S_;
  float*       srow  = scores + (plane * S_ + qrow) * S_;
  const _Float16* kpl = k  + plane * S_ * D_;
  const _Float16* vpl = vt + plane * D_ * S_;

  // Q B-fragments: lane provides Q[row=lr][k]
  f16x8 qa[4];
#pragma unroll
  for (int kk = 0; kk < 4; ++kk)
    qa[kk] = *(const f16x8*)(q + (plane * S_ + qrow) * D_ + kk * 32 + lh * 8);

  f32x4 o[8] = {};
  float m_r = -1e30f, l_r = 0.0f;

  _Float16* ksA = &KsBuf[0][0];
  _Float16* ksB = &KsBuf[1][0];
  _Float16* vtA = &VTsBuf[0][0];
  _Float16* vtB = &VTsBuf[1][0];

  // prologue: stage tile 0 into buffer A (512 threads, 2 rounds each of K,V)
#pragma unroll
  for (int i = 0; i < 2; ++i) {
    const int e = i * 4096 + tid * 8;
    const int krow = e >> 7;
    gll16(kpl + (size_t)krow * D_ + ((e & 127) ^ ((krow & 7) << 3)), ksA + e);
    const int vrow = e >> 6;
    gll16(vpl + (size_t)vrow * S_ + ((e & 63) ^ ((vrow & 7) << 3)), vtA + e);
  }
  __syncthreads();   // compiler drains vmcnt before s_barrier

  for (int tt = 0; tt < S_ / BT; ++tt) {
    const int t0 = tt * BT;

    // streams for THIS tile (needed after QK^T; deepest-issued)
    f32x4 pv4[4], pb4[4], mk4[4];
#pragma unroll
    for (int nt = 0; nt < 4; ++nt) {
      const int toff = t0 + nt * 16 + lh * 4;
      pv4[nt] = __builtin_nontemporal_load((const f32x4*)(prow + toff));
      pb4[nt] = *(const f32x4*)(pbrow + toff);
      mk4[nt] = *(const f32x4*)(mrow + toff);
    }
    // STAGE next tile into the other buffer (async DMA, drained at the
    // end-of-iteration barrier after the whole compute phase)
    if (tt < S_ / BT - 1) {
      const int t1 = t0 + BT;
#pragma unroll
      for (int i = 0; i < 2; ++i) {
        const int e = i * 4096 + tid * 8;
        const int krow = e >> 7;
        gll16(kpl + (size_t)(t1 + krow) * D_ + ((e & 127) ^ ((krow & 7) << 3)), ksB + e);
        const int vrow = e >> 6;
        gll16(vpl + (size_t)vrow * S_ + t1 + ((e & 63) ^ ((vrow & 7) << 3)), vtB + e);
      }
    }

    // QK^T swapped: sa[nt][r] = S[t = t0+nt*16+lh*4+r][q = qrow]
    f32x4 sa[4] = {};
    __builtin_amdgcn_s_setprio(1);
#pragma unroll
    for (int nt = 0; nt < 4; ++nt)
#pragma unroll
      for (int kk = 0; kk < 4; ++kk) {
        const int row = nt * 16 + lr;
        f16x8 kb = *(const f16x8*)(ksA + row * D_ + ((kk * 32 + lh * 8) ^ swz));
        sa[nt] = MFMA16(kb, qa[kk], sa[nt]);
      }
    __builtin_amdgcn_s_setprio(0);

    // epilogue: score = (qk+pb)/sqrtD + mask + prev ; pure VALU + store
#pragma unroll
    for (int nt = 0; nt < 4; ++nt) {
      const int toff = t0 + nt * 16 + lh * 4;
      f32x4 sc4 = (sa[nt] + pb4[nt]) * RSQRT_D + mk4[nt] + pv4[nt];
      __builtin_nontemporal_store(sc4, (f32x4*)(srow + toff));
      sa[nt] = sc4;
    }

    // online softmax, one q-row per lane; row group = lanes {l, l^16, l^32, l^48}
    float tmx = -1e30f;
#pragma unroll
    for (int nt = 0; nt < 4; ++nt)
#pragma unroll
      for (int r = 0; r < 4; ++r) tmx = fmaxf(tmx, sa[nt][r]);
    tmx = fmaxf(tmx, __shfl_xor(tmx, 16));
    tmx = fmaxf(tmx, __shfl_xor(tmx, 32));
    if (!__all(tmx <= m_r + 8.0f)) {   // T13 defer-max
      const float newm = fmaxf(m_r, tmx);
      const float al = __expf(m_r - newm);
      m_r = newm;
      l_r *= al;
#pragma unroll
      for (int nd = 0; nd < 8; ++nd) o[nd] *= al;
    }
    float ts = 0.0f;
#pragma unroll
    for (int nt = 0; nt < 4; ++nt)
#pragma unroll
      for (int r = 0; r < 4; ++r) {
        const float pe = __expf(sa[nt][r] - m_r);
        sa[nt][r] = pe;
        ts += pe;
      }
    ts += __shfl_xor(ts, 16);
    ts += __shfl_xor(ts, 32);
    l_r += ts;

    // P -> per-wave LDS [q=lr][t], swizzled, f16x4 stores (wave-local)
    _Float16* pw = &Ps[w][0];
#pragma unroll
    for (int nt = 0; nt < 4; ++nt) {
      f16x4 pk;
      pk[0] = (_Float16)sa[nt][0]; pk[1] = (_Float16)sa[nt][1];
      pk[2] = (_Float16)sa[nt][2]; pk[3] = (_Float16)sa[nt][3];
      *(f16x4*)(pw + lr * BT + ((nt * 16 + lh * 4) ^ swz)) = pk;
    }

    // PV swapped: o[nd][r] = ctx[d = nd*16+lh*4+r][q = qrow]
    __builtin_amdgcn_s_setprio(1);
#pragma unroll
    for (int kk2 = 0; kk2 < 2; ++kk2) {
      const f16x8 pa = *(const f16x8*)(pw + lr * BT + ((kk2 * 32 + lh * 8) ^ swz));
#pragma unroll
      for (int nd = 0; nd < 8; ++nd) {
        const int vr = nd * 16 + lr;
        const f16x8 vb = *(const f16x8*)(vtA + vr * BT + ((kk2 * 32 + lh * 8) ^ swz));
        o[nd] = MFMA16(vb, pa, o[nd]);
      }
    }
    __builtin_amdgcn_s_setprio(0);

    // sole drain point: waits this wave's gll16s + ds ops, then barrier
    __syncthreads();
    _Float16* t1p = ksA; ksA = ksB; ksB = t1p;
    _Float16* t2p = vtA; vtA = vtB; vtB = t2p;
  }

  // ctx write: lane owns q-row qrow, d = nd*16 + lh*4 + r -> f16x4 stores
  const float inv_l = 1.0f / l_r;
  _Float16* crow = ctx + ((size_t)(b * S_) + qrow) * HID_ + h * D_;
#pragma unroll
  for (int nd = 0; nd < 8; ++nd) {
    f16x4 cv;
#pragma unroll
    for (int r = 0; r < 4; ++r) cv[r] = (_Float16)(o[nd][r] * inv_l);
    *(f16x4*)(crow + nd * 16 + lh * 4) = cv;
  }
}

// ---------------------------------------------------------------------------
extern "C" void kernel_launch(void* const* d_in, const int* in_sizes, int n_in,
                              void* d_out, int out_size, void* d_ws, size_t ws_size,
                              hipStream_t stream) {
  const float* query = (const float*)d_in[0];
  const float* key_i = (const float*)d_in[1];
  const float* value = (const float*)d_in[2];
  const float* maskp = (const float*)d_in[3];
  const float* pbias = (const float*)d_in[4];
  const float* prev  = (const float*)d_in[5];
  const int*   pids  = (const int*)d_in[6];
  const float* Wq = (const float*)d_in[7];
  const float* bq = (const float*)d_in[8];
  const float* Wk = (const float*)d_in[9];
  const float* bk = (const float*)d_in[10];
  const float* Wv = (const float*)d_in[11];
  const float* bv = (const float*)d_in[12];
  const float* Wo = (const float*)d_in[13];
  const float* bo = (const float*)d_in[14];

  char* ws = (char*)d_ws;
  // workspace layout (bytes); total need = 134,479,872
  const size_t OFF_TCOS = 0;
  const size_t OFF_TSIN = 131072;
  const size_t OFF_W    = 262144;                      // 4 x 8 MB f16 weights
  const size_t OFF_X    = OFF_W + 4ull * 8388608;      // 3 x 16 MB f16 X
  const size_t OFF_Q    = OFF_X + 3ull * 16777216;
  const size_t OFF_K    = OFF_Q + 16777216;
  const size_t OFF_VT   = OFF_K + 16777216;            // V proj writes here (B,H,D,S)
  const size_t OFF_CTX  = OFF_X + 16777216;            // reuse Xk (consumed)

  float* tcos = (float*)(ws + OFF_TCOS);
  float* tsin = (float*)(ws + OFF_TSIN);
  _Float16* Wq16 = (_Float16*)(ws + OFF_W);
  _Float16* Wk16 = (_Float16*)(ws + OFF_W + 8388608);
  _Float16* Wv16 = (_Float16*)(ws + OFF_W + 2ull * 8388608);
  _Float16* Wo16 = (_Float16*)(ws + OFF_W + 3ull * 8388608);
  _Float16* Xq16 = (_Float16*)(ws + OFF_X);
  _Float16* Xk16 = (_Float16*)(ws + OFF_X + 16777216);
  _Float16* Xv16 = (_Float16*)(ws + OFF_X + 2ull * 16777216);
  _Float16* q16  = (_Float16*)(ws + OFF_Q);
  _Float16* k16  = (_Float16*)(ws + OFF_K);
  _Float16* vt16 = (_Float16*)(ws + OFF_VT);
  _Float16* ctx16 = (_Float16*)(ws + OFF_CTX);

  float* out_f32 = (float*)d_out;                 // (B,S,HID) = 8,388,608
  float* scores  = (float*)d_out + 8388608;       // (B,H,S,S) = 67,108,864

  rope_table_kernel<<<128, 256, 0, stream>>>(tcos, tsin);

  cvt_kernel<<<2048, 256, 0, stream>>>(Wq, Wq16, 524288);
  cvt_kernel<<<2048, 256, 0, stream>>>(Wk, Wk16, 524288);
  cvt_kernel<<<2048, 256, 0, stream>>>(Wv, Wv16, 524288);
  cvt_kernel<<<2048, 256, 0, stream>>>(Wo, Wo16, 524288);
  cvt_kernel<<<4096, 256, 0, stream>>>(query, Xq16, 1048576);
  cvt_kernel<<<4096, 256, 0, stream>>>(key_i, Xk16, 1048576);
  cvt_kernel<<<4096, 256, 0, stream>>>(value, Xv16, 1048576);

  proj_kernel<0><<<512, 256, 0, stream>>>(Xq16, Wq16, bq, (void*)q16, pids, tcos, tsin);
  proj_kernel<0><<<512, 256, 0, stream>>>(Xk16, Wk16, bk, (void*)k16, pids, tcos, tsin);
  proj_kernel<1><<<512, 256, 0, stream>>>(Xv16, Wv16, bv, (void*)vt16, nullptr, nullptr, nullptr);

  flash_kernel<<<512, 512, 0, stream>>>(q16, k16, vt16, pbias, maskp, prev,
                                        scores, ctx16);

  proj_kernel<2><<<512, 256, 0, stream>>>(ctx16, Wo16, bo, (void*)out_f32,
                                          nullptr, nullptr, nullptr);
}

// Round 10
// 488.808 us; speedup vs baseline: 1.0253x; 1.0002x over previous
//
#include <hip/hip_runtime.h>

// ---------------------------------------------------------------------------
// GLMAttention: qkv proj (+RoPE) -> fused flash attn (scores out + softmax+PV)
// -> output proj.  All matmuls fp16 MFMA (16x16x32), f32 accumulate.
// B=4 S=1024 HID=2048 H=16 D=128.
// Round 10: flash = r9 schedule (BT=64, 2-phase dbuf, 512 thr / 8 waves) but
// P redistributed IN-REGISTER (16 shfl + 8 selects within 4-lane groups)
// instead of via LDS. LDS 80KB -> 64KB exactly -> 2 blocks/CU = 16 waves/CU.
// ---------------------------------------------------------------------------

#define B_  4
#define S_  1024
#define HID_ 2048
#define H_  16
#define D_  128
#define RSQRT_D 0.08838834764831845f

typedef _Float16 f16x8 __attribute__((ext_vector_type(8)));
typedef _Float16 f16x4 __attribute__((ext_vector_type(4)));
typedef float f32x4 __attribute__((ext_vector_type(4)));
typedef unsigned int u32x2 __attribute__((ext_vector_type(2)));
typedef unsigned int u32x4 __attribute__((ext_vector_type(4)));

#define MFMA16(a, b, c) __builtin_amdgcn_mfma_f32_16x16x32_f16(a, b, c, 0, 0, 0)

__device__ __forceinline__ void gll16(const void* g, void* l) {
  __builtin_amdgcn_global_load_lds(
      (const __attribute__((address_space(1))) void*)g,
      (__attribute__((address_space(3))) void*)l, 16, 0, 0);
}

// ---------------------------------------------------------------------------
// RoPE tables: cos/sin[pos][j], j in [0,32), inv_freq = 10000^(-j/32)
// ---------------------------------------------------------------------------
__global__ void rope_table_kernel(float* __restrict__ tcos, float* __restrict__ tsin) {
  int i = blockIdx.x * blockDim.x + threadIdx.x;  // 32768 = 1024*32
  int pos = i >> 5, j = i & 31;
  float inv = expf(-(float)j * (9.210340371976184f / 32.0f));  // ln(10000)/32
  float ang = (float)pos * inv;
  tcos[i] = cosf(ang);
  tsin[i] = sinf(ang);
}

// ---------------------------------------------------------------------------
// f32 -> f16 convert, 8 elems/thread, vectorized
// ---------------------------------------------------------------------------
__global__ void cvt_kernel(const float* __restrict__ in, _Float16* __restrict__ out, int n8) {
  int i = blockIdx.x * blockDim.x + threadIdx.x;
  if (i >= n8) return;
  const f32x4* in4 = (const f32x4*)in;
  f32x4 a = in4[i * 2], b = in4[i * 2 + 1];
  f16x8 v;
  v[0] = (_Float16)a[0]; v[1] = (_Float16)a[1]; v[2] = (_Float16)a[2]; v[3] = (_Float16)a[3];
  v[4] = (_Float16)b[0]; v[5] = (_Float16)b[1]; v[6] = (_Float16)b[2]; v[7] = (_Float16)b[3];
  *(f16x8*)(out + (size_t)i * 8) = v;
}

// ---------------------------------------------------------------------------
// GEMM: C = A(MxK) @ W(NxK)^T + bias.  128x128 tile, BK=64, 4 waves, 4x4 frags.
// MODE 0: RoPE epilogue  -> f16 out (B,H,S,D)
// MODE 1: V head, transposed -> f16 out (B,H,D,S)
// MODE 2: f32 + bias     -> f32 out (M,N)  (final output)
// ---------------------------------------------------------------------------
template <int MODE>
__global__ __launch_bounds__(256) void proj_kernel(
    const _Float16* __restrict__ A, const _Float16* __restrict__ Bw,
    const float* __restrict__ bias, void* __restrict__ outp,
    const int* __restrict__ pids, const float* __restrict__ tcos,
    const float* __restrict__ tsin) {
  constexpr int N = HID_, K = HID_;
  constexpr int BK = 64;
  __shared__ _Float16 As[128 * BK];
  __shared__ _Float16 Bs[128 * BK];

  const int tid = threadIdx.x;
  // XCD-aware swizzle (512 blocks, 512%8==0 -> bijective)
  const int bid = (blockIdx.x & 7) * 64 + (blockIdx.x >> 3);
  const int tm = bid >> 4, tn = bid & 15;  // 32 x 16 tiles
  const int m0 = tm * 128, n0 = tn * 128;
  const int w = tid >> 6, l = tid & 63;
  const int mw = (w >> 1) * 64, nw = (w & 1) * 64;
  const int lr = l & 15, lh = l >> 4;

  f32x4 acc[4][4] = {};

  for (int kt = 0; kt < K / BK; ++kt) {
    const int k0 = kt * BK;
    __syncthreads();
#pragma unroll
    for (int i = 0; i < 4; ++i) {
      const int e = i * 2048 + tid * 8;
      gll16(A + (size_t)(m0 + (e >> 6)) * K + k0 + (e & 63), As + e);
      gll16(Bw + (size_t)(n0 + (e >> 6)) * K + k0 + (e & 63), Bs + e);
    }
    asm volatile("s_waitcnt vmcnt(0)" ::: "memory");
    __syncthreads();
#pragma unroll
    for (int kk = 0; kk < 2; ++kk) {
      f16x8 af[4], bf[4];
#pragma unroll
      for (int mi = 0; mi < 4; ++mi)
        af[mi] = *(const f16x8*)(As + (mw + mi * 16 + lr) * BK + kk * 32 + lh * 8);
#pragma unroll
      for (int ni = 0; ni < 4; ++ni)
        bf[ni] = *(const f16x8*)(Bs + (nw + ni * 16 + lr) * BK + kk * 32 + lh * 8);
#pragma unroll
      for (int mi = 0; mi < 4; ++mi)
#pragma unroll
        for (int ni = 0; ni < 4; ++ni)
          acc[mi][ni] = MFMA16(af[mi], bf[ni], acc[mi][ni]);
    }
  }

  if constexpr (MODE == 2) {
    float* out = (float*)outp;
#pragma unroll
    for (int mi = 0; mi < 4; ++mi)
#pragma unroll
      for (int ni = 0; ni < 4; ++ni) {
        const int col = n0 + nw + ni * 16 + lr;
        const float bb = bias[col];
#pragma unroll
        for (int r = 0; r < 4; ++r) {
          const int row = m0 + mw + mi * 16 + lh * 4 + r;
          out[(size_t)row * N + col] = acc[mi][ni][r] + bb;
        }
      }
  } else if constexpr (MODE == 1) {  // V: write (B,H,D,S) directly
    _Float16* out = (_Float16*)outp;
#pragma unroll
    for (int mi = 0; mi < 4; ++mi)
#pragma unroll
      for (int ni = 0; ni < 4; ++ni) {
        const int col = n0 + nw + ni * 16 + lr;
        const float bb = bias[col];
        const int h = col >> 7, hd = col & 127;
#pragma unroll
        for (int r = 0; r < 4; ++r) {
          const int row = m0 + mw + mi * 16 + lh * 4 + r;
          const int b = row >> 10, s = row & 1023;
          out[(((size_t)(b * H_ + h)) * D_ + hd) * S_ + s] = (_Float16)(acc[mi][ni][r] + bb);
        }
      }
  } else {  // MODE 0: RoPE. wave covers cols [c0,c0+64) = head dims [0,64) or [64,128)
    _Float16* out = (_Float16*)outp;
    const int sel = (nw >> 6) & 1;  // 0 -> pid row, 1 -> bid row of position_ids
#pragma unroll
    for (int mi = 0; mi < 4; ++mi) {
#pragma unroll
      for (int r = 0; r < 4; ++r) {
        const int row = m0 + mw + mi * 16 + lh * 4 + r;
        const int b = row >> 10, s = row & 1023;
        const int pos = pids[b * 2 * S_ + sel * S_ + s];
#pragma unroll
        for (int ni = 0; ni < 2; ++ni) {
          const int col = n0 + nw + ni * 16 + lr;  // first of (d, d+32) pair
          const int j = ni * 16 + lr;              // 0..31 freq index
          const float c = tcos[pos * 32 + j];
          const float sn = tsin[pos * 32 + j];
          const float x1 = acc[mi][ni][r] + bias[col];
          const float x2 = acc[mi][ni + 2][r] + bias[col + 32];
          const int h = col >> 7, hd = col & 127;
          const size_t base = (((size_t)(b * H_ + h)) * S_ + s) * D_;
          out[base + hd] = (_Float16)(x1 * c - x2 * sn);
          out[base + hd + 32] = (_Float16)(x2 * c + x1 * sn);
        }
      }
    }
  }
}

// ---------------------------------------------------------------------------
// Fused flash attention, 2-phase double-buffered, BT=64, 8 waves/block,
// NO P-LDS: P redistributed in-register.
// Lane (lr,lh) after swapped QK^T holds P[t0 + nt*16 + lh*4 + r][q0+lr].
// PV B-operand needs P[t0 + kk2*32 + lh*8 + j][q0+lr] =
//   word (j&3) of sa[2*kk2 + (lh>>1)] from lane lr + 16*(2*(lh&1) + (j>>2)).
// -> 16 __shfl + 8 selects within the 4-lane group {l, l^16, l^32, l^48}.
// LDS = K/V double-buffer only, 64 KB -> 2 blocks/CU = 16 waves/CU.
// ---------------------------------------------------------------------------
__global__ __launch_bounds__(512) void flash_kernel(
    const _Float16* __restrict__ q, const _Float16* __restrict__ k,
    const _Float16* __restrict__ vt, const float* __restrict__ pbias,
    const float* __restrict__ maskp, const float* __restrict__ prev,
    float* __restrict__ scores, _Float16* __restrict__ ctx) {
  constexpr int BT = 64;
  __shared__ _Float16 KsBuf[2][BT * D_];   // [t][d] swizzled, 2 x 16 KB
  __shared__ _Float16 VTsBuf[2][D_ * BT];  // [d][t] swizzled, 2 x 16 KB

  const int tid = threadIdx.x, w = tid >> 6, l = tid & 63;
  const int lr = l & 15, lh = l >> 4;
  // XCD swizzle: 512 blocks -> 64 consecutive per XCD (8 planes/XCD)
  const int sid = (blockIdx.x & 7) * 64 + (blockIdx.x >> 3);
  const int qt = sid & 7, byh = sid >> 3;
  const int b = byh >> 4, h = byh & 15;
  const size_t plane = (size_t)byh;
  const int q0 = qt * 128 + w * 16;   // 8 waves x 16 rows = 128 rows/block
  const int qrow = q0 + lr;           // this lane's q-row
  const int swz = (lr & 7) << 3;      // element-index XOR for frag reads

  // P-exchange lane indices (4-lane group, stride 16)
  const int srcA = lr + ((l & 16) << 1);  // lr + 32*(lh&1)
  const int srcB = srcA + 16;
  const bool selHi = (l & 32) != 0;       // lh>>1

  const float* prow  = prev  + (plane * S_ + qrow) * S_;
  const float* pbrow = pbias + ((size_t)h * S_ + qrow) * S_;
  const float* mrow  = maskp + ((size_t)b * S_ + qrow) * S_;
  float*       srow  = scores + (plane * S_ + qrow) * S_;
  const _Float16* kpl = k  + plane * S_ * D_;
  const _Float16* vpl = vt + plane * D_ * S_;

  // Q B-fragments: lane provides Q[row=lr][k]
  f16x8 qa[4];
#pragma unroll
  for (int kk = 0; kk < 4; ++kk)
    qa[kk] = *(const f16x8*)(q + (plane * S_ + qrow) * D_ + kk * 32 + lh * 8);

  f32x4 o[8] = {};
  float m_r = -1e30f, l_r = 0.0f;

  _Float16* ksA = &KsBuf[0][0];
  _Float16* ksB = &KsBuf[1][0];
  _Float16* vtA = &VTsBuf[0][0];
  _Float16* vtB = &VTsBuf[1][0];

  // prologue: stage tile 0 into buffer A (512 threads, 2 rounds each of K,V)
#pragma unroll
  for (int i = 0; i < 2; ++i) {
    const int e = i * 4096 + tid * 8;
    const int krow = e >> 7;
    gll16(kpl + (size_t)krow * D_ + ((e & 127) ^ ((krow & 7) << 3)), ksA + e);
    const int vrow = e >> 6;
    gll16(vpl + (size_t)vrow * S_ + ((e & 63) ^ ((vrow & 7) << 3)), vtA + e);
  }
  __syncthreads();   // compiler drains vmcnt before s_barrier

  for (int tt = 0; tt < S_ / BT; ++tt) {
    const int t0 = tt * BT;

    // streams for THIS tile (needed after QK^T; deepest-issued)
    f32x4 pv4[4], pb4[4], mk4[4];
#pragma unroll
    for (int nt = 0; nt < 4; ++nt) {
      const int toff = t0 + nt * 16 + lh * 4;
      pv4[nt] = __builtin_nontemporal_load((const f32x4*)(prow + toff));
      pb4[nt] = *(const f32x4*)(pbrow + toff);
      mk4[nt] = *(const f32x4*)(mrow + toff);
    }
    // STAGE next tile into the other buffer (async DMA, drained at the
    // end-of-iteration barrier after the whole compute phase)
    if (tt < S_ / BT - 1) {
      const int t1 = t0 + BT;
#pragma unroll
      for (int i = 0; i < 2; ++i) {
        const int e = i * 4096 + tid * 8;
        const int krow = e >> 7;
        gll16(kpl + (size_t)(t1 + krow) * D_ + ((e & 127) ^ ((krow & 7) << 3)), ksB + e);
        const int vrow = e >> 6;
        gll16(vpl + (size_t)vrow * S_ + t1 + ((e & 63) ^ ((vrow & 7) << 3)), vtB + e);
      }
    }

    // QK^T swapped: sa[nt][r] = S[t = t0+nt*16+lh*4+r][q = qrow]
    f32x4 sa[4] = {};
    __builtin_amdgcn_s_setprio(1);
#pragma unroll
    for (int nt = 0; nt < 4; ++nt)
#pragma unroll
      for (int kk = 0; kk < 4; ++kk) {
        const int row = nt * 16 + lr;
        f16x8 kb = *(const f16x8*)(ksA + row * D_ + ((kk * 32 + lh * 8) ^ swz));
        sa[nt] = MFMA16(kb, qa[kk], sa[nt]);
      }
    __builtin_amdgcn_s_setprio(0);

    // epilogue: score = (qk+pb)/sqrtD + mask + prev ; pure VALU + store
#pragma unroll
    for (int nt = 0; nt < 4; ++nt) {
      const int toff = t0 + nt * 16 + lh * 4;
      f32x4 sc4 = (sa[nt] + pb4[nt]) * RSQRT_D + mk4[nt] + pv4[nt];
      __builtin_nontemporal_store(sc4, (f32x4*)(srow + toff));
      sa[nt] = sc4;
    }

    // online softmax, one q-row per lane; row group = lanes {l, l^16, l^32, l^48}
    float tmx = -1e30f;
#pragma unroll
    for (int nt = 0; nt < 4; ++nt)
#pragma unroll
      for (int r = 0; r < 4; ++r) tmx = fmaxf(tmx, sa[nt][r]);
    tmx = fmaxf(tmx, __shfl_xor(tmx, 16));
    tmx = fmaxf(tmx, __shfl_xor(tmx, 32));
    if (!__all(tmx <= m_r + 8.0f)) {   // T13 defer-max
      const float newm = fmaxf(m_r, tmx);
      const float al = __expf(m_r - newm);
      m_r = newm;
      l_r *= al;
#pragma unroll
      for (int nd = 0; nd < 8; ++nd) o[nd] *= al;
    }
    float ts = 0.0f;
#pragma unroll
    for (int nt = 0; nt < 4; ++nt)
#pragma unroll
      for (int r = 0; r < 4; ++r) {
        const float pe = __expf(sa[nt][r] - m_r);
        sa[nt][r] = pe;
        ts += pe;
      }
    ts += __shfl_xor(ts, 16);
    ts += __shfl_xor(ts, 32);
    l_r += ts;

    // ---- P redistribution in-register (no LDS) ----
    // pack each sa[nt] (4 f32) -> f16x4 -> 2 u32 words
    unsigned int u0w0, u0w1, u1w0, u1w1, u2w0, u2w1, u3w0, u3w1;
    {
      f16x4 pk0, pk1, pk2, pk3;
#pragma unroll
      for (int r = 0; r < 4; ++r) {
        pk0[r] = (_Float16)sa[0][r]; pk1[r] = (_Float16)sa[1][r];
        pk2[r] = (_Float16)sa[2][r]; pk3[r] = (_Float16)sa[3][r];
      }
      u32x2 v0 = __builtin_bit_cast(u32x2, pk0); u0w0 = v0[0]; u0w1 = v0[1];
      u32x2 v1 = __builtin_bit_cast(u32x2, pk1); u1w0 = v1[0]; u1w1 = v1[1];
      u32x2 v2 = __builtin_bit_cast(u32x2, pk2); u2w0 = v2[0]; u2w1 = v2[1];
      u32x2 v3 = __builtin_bit_cast(u32x2, pk3); u3w0 = v3[0]; u3w1 = v3[1];
    }
    // gather both candidate nt words from both source lanes, select by lh>>1
    const unsigned a00 = (unsigned)__shfl((int)u0w0, srcA), a01 = (unsigned)__shfl((int)u0w1, srcA);
    const unsigned a10 = (unsigned)__shfl((int)u1w0, srcA), a11 = (unsigned)__shfl((int)u1w1, srcA);
    const unsigned a20 = (unsigned)__shfl((int)u2w0, srcA), a21 = (unsigned)__shfl((int)u2w1, srcA);
    const unsigned a30 = (unsigned)__shfl((int)u3w0, srcA), a31 = (unsigned)__shfl((int)u3w1, srcA);
    const unsigned b00 = (unsigned)__shfl((int)u0w0, srcB), b01 = (unsigned)__shfl((int)u0w1, srcB);
    const unsigned b10 = (unsigned)__shfl((int)u1w0, srcB), b11 = (unsigned)__shfl((int)u1w1, srcB);
    const unsigned b20 = (unsigned)__shfl((int)u2w0, srcB), b21 = (unsigned)__shfl((int)u2w1, srcB);
    const unsigned b30 = (unsigned)__shfl((int)u3w0, srcB), b31 = (unsigned)__shfl((int)u3w1, srcB);
    u32x4 paw0, paw1;  // pa for kk2=0 (nt 0/1) and kk2=1 (nt 2/3)
    paw0[0] = selHi ? a10 : a00; paw0[1] = selHi ? a11 : a01;
    paw0[2] = selHi ? b10 : b00; paw0[3] = selHi ? b11 : b01;
    paw1[0] = selHi ? a30 : a20; paw1[1] = selHi ? a31 : a21;
    paw1[2] = selHi ? b30 : b20; paw1[3] = selHi ? b31 : b21;
    const f16x8 pa0 = __builtin_bit_cast(f16x8, paw0);
    const f16x8 pa1 = __builtin_bit_cast(f16x8, paw1);

    // PV swapped: o[nd][r] = ctx[d = nd*16+lh*4+r][q = qrow]
    __builtin_amdgcn_s_setprio(1);
#pragma unroll
    for (int nd = 0; nd < 8; ++nd) {
      const int vr = nd * 16 + lr;
      const f16x8 vb0 = *(const f16x8*)(vtA + vr * BT + ((lh * 8) ^ swz));
      o[nd] = MFMA16(vb0, pa0, o[nd]);
    }
#pragma unroll
    for (int nd = 0; nd < 8; ++nd) {
      const int vr = nd * 16 + lr;
      const f16x8 vb1 = *(const f16x8*)(vtA + vr * BT + ((32 + lh * 8) ^ swz));
      o[nd] = MFMA16(vb1, pa1, o[nd]);
    }
    __builtin_amdgcn_s_setprio(0);

    // sole drain point: waits this wave's gll16s, then barrier
    __syncthreads();
    _Float16* t1p = ksA; ksA = ksB; ksB = t1p;
    _Float16* t2p = vtA; vtA = vtB; vtB = t2p;
  }

  // ctx write: lane owns q-row qrow, d = nd*16 + lh*4 + r -> f16x4 stores
  const float inv_l = 1.0f / l_r;
  _Float16* crow = ctx + ((size_t)(b * S_) + qrow) * HID_ + h * D_;
#pragma unroll
  for (int nd = 0; nd < 8; ++nd) {
    f16x4 cv;
#pragma unroll
    for (int r = 0; r < 4; ++r) cv[r] = (_Float16)(o[nd][r] * inv_l);
    *(f16x4*)(crow + nd * 16 + lh * 4) = cv;
  }
}

// ---------------------------------------------------------------------------
extern "C" void kernel_launch(void* const* d_in, const int* in_sizes, int n_in,
                              void* d_out, int out_size, void* d_ws, size_t ws_size,
                              hipStream_t stream) {
  const float* query = (const float*)d_in[0];
  const float* key_i = (const float*)d_in[1];
  const float* value = (const float*)d_in[2];
  const float* maskp = (const float*)d_in[3];
  const float* pbias = (const float*)d_in[4];
  const float* prev  = (const float*)d_in[5];
  const int*   pids  = (const int*)d_in[6];
  const float* Wq = (const float*)d_in[7];
  const float* bq = (const float*)d_in[8];
  const float* Wk = (const float*)d_in[9];
  const float* bk = (const float*)d_in[10];
  const float* Wv = (const float*)d_in[11];
  const float* bv = (const float*)d_in[12];
  const float* Wo = (const float*)d_in[13];
  const float* bo = (const float*)d_in[14];

  char* ws = (char*)d_ws;
  // workspace layout (bytes); total need = 134,479,872
  const size_t OFF_TCOS = 0;
  const size_t OFF_TSIN = 131072;
  const size_t OFF_W    = 262144;                      // 4 x 8 MB f16 weights
  const size_t OFF_X    = OFF_W + 4ull * 8388608;      // 3 x 16 MB f16 X
  const size_t OFF_Q    = OFF_X + 3ull * 16777216;
  const size_t OFF_K    = OFF_Q + 16777216;
  const size_t OFF_VT   = OFF_K + 16777216;            // V proj writes here (B,H,D,S)
  const size_t OFF_CTX  = OFF_X + 16777216;            // reuse Xk (consumed)

  float* tcos = (float*)(ws + OFF_TCOS);
  float* tsin = (float*)(ws + OFF_TSIN);
  _Float16* Wq16 = (_Float16*)(ws + OFF_W);
  _Float16* Wk16 = (_Float16*)(ws + OFF_W + 8388608);
  _Float16* Wv16 = (_Float16*)(ws + OFF_W + 2ull * 8388608);
  _Float16* Wo16 = (_Float16*)(ws + OFF_W + 3ull * 8388608);
  _Float16* Xq16 = (_Float16*)(ws + OFF_X);
  _Float16* Xk16 = (_Float16*)(ws + OFF_X + 16777216);
  _Float16* Xv16 = (_Float16*)(ws + OFF_X + 2ull * 16777216);
  _Float16* q16  = (_Float16*)(ws + OFF_Q);
  _Float16* k16  = (_Float16*)(ws + OFF_K);
  _Float16* vt16 = (_Float16*)(ws + OFF_VT);
  _Float16* ctx16 = (_Float16*)(ws + OFF_CTX);

  float* out_f32 = (float*)d_out;                 // (B,S,HID) = 8,388,608
  float* scores  = (float*)d_out + 8388608;       // (B,H,S,S) = 67,108,864

  rope_table_kernel<<<128, 256, 0, stream>>>(tcos, tsin);

  cvt_kernel<<<2048, 256, 0, stream>>>(Wq, Wq16, 524288);
  cvt_kernel<<<2048, 256, 0, stream>>>(Wk, Wk16, 524288);
  cvt_kernel<<<2048, 256, 0, stream>>>(Wv, Wv16, 524288);
  cvt_kernel<<<2048, 256, 0, stream>>>(Wo, Wo16, 524288);
  cvt_kernel<<<4096, 256, 0, stream>>>(query, Xq16, 1048576);
  cvt_kernel<<<4096, 256, 0, stream>>>(key_i, Xk16, 1048576);
  cvt_kernel<<<4096, 256, 0, stream>>>(value, Xv16, 1048576);

  proj_kernel<0><<<512, 256, 0, stream>>>(Xq16, Wq16, bq, (void*)q16, pids, tcos, tsin);
  proj_kernel<0><<<512, 256, 0, stream>>>(Xk16, Wk16, bk, (void*)k16, pids, tcos, tsin);
  proj_kernel<1><<<512, 256, 0, stream>>>(Xv16, Wv16, bv, (void*)vt16, nullptr, nullptr, nullptr);

  flash_kernel<<<512, 512, 0, stream>>>(q16, k16, vt16, pbias, maskp, prev,
                                        scores, ctx16);

  proj_kernel<2><<<512, 256, 0, stream>>>(ctx16, Wo16, bo, (void*)out_f32,
                                          nullptr, nullptr, nullptr);
}

// Round 11
// 487.485 us; speedup vs baseline: 1.0281x; 1.0027x over previous
//
#include <hip/hip_runtime.h>

// ---------------------------------------------------------------------------
// GLMAttention: qkv proj (+RoPE) -> fused flash attn (scores out + softmax+PV)
// -> output proj.  All matmuls fp16 MFMA (16x16x32), f32 accumulate.
// B=4 S=1024 HID=2048 H=16 D=128.
// Round 11: r10 + prev prefetched ONE ITERATION AHEAD (pvA/pvB static swap).
// prev is the only always-HBM-miss stream (256MB unique); pb/mask are
// L2-resident (4x/16x reuse). Issue order pb/mk -> pvB -> stage keeps the
// epilogue's wait shallow (vmcnt in-order).
// ---------------------------------------------------------------------------

#define B_  4
#define S_  1024
#define HID_ 2048
#define H_  16
#define D_  128
#define RSQRT_D 0.08838834764831845f

typedef _Float16 f16x8 __attribute__((ext_vector_type(8)));
typedef _Float16 f16x4 __attribute__((ext_vector_type(4)));
typedef float f32x4 __attribute__((ext_vector_type(4)));
typedef unsigned int u32x2 __attribute__((ext_vector_type(2)));
typedef unsigned int u32x4 __attribute__((ext_vector_type(4)));

#define MFMA16(a, b, c) __builtin_amdgcn_mfma_f32_16x16x32_f16(a, b, c, 0, 0, 0)

__device__ __forceinline__ void gll16(const void* g, void* l) {
  __builtin_amdgcn_global_load_lds(
      (const __attribute__((address_space(1))) void*)g,
      (__attribute__((address_space(3))) void*)l, 16, 0, 0);
}

// ---------------------------------------------------------------------------
// RoPE tables: cos/sin[pos][j], j in [0,32), inv_freq = 10000^(-j/32)
// ---------------------------------------------------------------------------
__global__ void rope_table_kernel(float* __restrict__ tcos, float* __restrict__ tsin) {
  int i = blockIdx.x * blockDim.x + threadIdx.x;  // 32768 = 1024*32
  int pos = i >> 5, j = i & 31;
  float inv = expf(-(float)j * (9.210340371976184f / 32.0f));  // ln(10000)/32
  float ang = (float)pos * inv;
  tcos[i] = cosf(ang);
  tsin[i] = sinf(ang);
}

// ---------------------------------------------------------------------------
// f32 -> f16 convert, 8 elems/thread, vectorized
// ---------------------------------------------------------------------------
__global__ void cvt_kernel(const float* __restrict__ in, _Float16* __restrict__ out, int n8) {
  int i = blockIdx.x * blockDim.x + threadIdx.x;
  if (i >= n8) return;
  const f32x4* in4 = (const f32x4*)in;
  f32x4 a = in4[i * 2], b = in4[i * 2 + 1];
  f16x8 v;
  v[0] = (_Float16)a[0]; v[1] = (_Float16)a[1]; v[2] = (_Float16)a[2]; v[3] = (_Float16)a[3];
  v[4] = (_Float16)b[0]; v[5] = (_Float16)b[1]; v[6] = (_Float16)b[2]; v[7] = (_Float16)b[3];
  *(f16x8*)(out + (size_t)i * 8) = v;
}

// ---------------------------------------------------------------------------
// GEMM: C = A(MxK) @ W(NxK)^T + bias.  128x128 tile, BK=64, 4 waves, 4x4 frags.
// MODE 0: RoPE epilogue  -> f16 out (B,H,S,D)
// MODE 1: V head, transposed -> f16 out (B,H,D,S)
// MODE 2: f32 + bias     -> f32 out (M,N)  (final output)
// ---------------------------------------------------------------------------
template <int MODE>
__global__ __launch_bounds__(256) void proj_kernel(
    const _Float16* __restrict__ A, const _Float16* __restrict__ Bw,
    const float* __restrict__ bias, void* __restrict__ outp,
    const int* __restrict__ pids, const float* __restrict__ tcos,
    const float* __restrict__ tsin) {
  constexpr int N = HID_, K = HID_;
  constexpr int BK = 64;
  __shared__ _Float16 As[128 * BK];
  __shared__ _Float16 Bs[128 * BK];

  const int tid = threadIdx.x;
  // XCD-aware swizzle (512 blocks, 512%8==0 -> bijective)
  const int bid = (blockIdx.x & 7) * 64 + (blockIdx.x >> 3);
  const int tm = bid >> 4, tn = bid & 15;  // 32 x 16 tiles
  const int m0 = tm * 128, n0 = tn * 128;
  const int w = tid >> 6, l = tid & 63;
  const int mw = (w >> 1) * 64, nw = (w & 1) * 64;
  const int lr = l & 15, lh = l >> 4;

  f32x4 acc[4][4] = {};

  for (int kt = 0; kt < K / BK; ++kt) {
    const int k0 = kt * BK;
    __syncthreads();
#pragma unroll
    for (int i = 0; i < 4; ++i) {
      const int e = i * 2048 + tid * 8;
      gll16(A + (size_t)(m0 + (e >> 6)) * K + k0 + (e & 63), As + e);
      gll16(Bw + (size_t)(n0 + (e >> 6)) * K + k0 + (e & 63), Bs + e);
    }
    asm volatile("s_waitcnt vmcnt(0)" ::: "memory");
    __syncthreads();
#pragma unroll
    for (int kk = 0; kk < 2; ++kk) {
      f16x8 af[4], bf[4];
#pragma unroll
      for (int mi = 0; mi < 4; ++mi)
        af[mi] = *(const f16x8*)(As + (mw + mi * 16 + lr) * BK + kk * 32 + lh * 8);
#pragma unroll
      for (int ni = 0; ni < 4; ++ni)
        bf[ni] = *(const f16x8*)(Bs + (nw + ni * 16 + lr) * BK + kk * 32 + lh * 8);
#pragma unroll
      for (int mi = 0; mi < 4; ++mi)
#pragma unroll
        for (int ni = 0; ni < 4; ++ni)
          acc[mi][ni] = MFMA16(af[mi], bf[ni], acc[mi][ni]);
    }
  }

  if constexpr (MODE == 2) {
    float* out = (float*)outp;
#pragma unroll
    for (int mi = 0; mi < 4; ++mi)
#pragma unroll
      for (int ni = 0; ni < 4; ++ni) {
        const int col = n0 + nw + ni * 16 + lr;
        const float bb = bias[col];
#pragma unroll
        for (int r = 0; r < 4; ++r) {
          const int row = m0 + mw + mi * 16 + lh * 4 + r;
          out[(size_t)row * N + col] = acc[mi][ni][r] + bb;
        }
      }
  } else if constexpr (MODE == 1) {  // V: write (B,H,D,S) directly
    _Float16* out = (_Float16*)outp;
#pragma unroll
    for (int mi = 0; mi < 4; ++mi)
#pragma unroll
      for (int ni = 0; ni < 4; ++ni) {
        const int col = n0 + nw + ni * 16 + lr;
        const float bb = bias[col];
        const int h = col >> 7, hd = col & 127;
#pragma unroll
        for (int r = 0; r < 4; ++r) {
          const int row = m0 + mw + mi * 16 + lh * 4 + r;
          const int b = row >> 10, s = row & 1023;
          out[(((size_t)(b * H_ + h)) * D_ + hd) * S_ + s] = (_Float16)(acc[mi][ni][r] + bb);
        }
      }
  } else {  // MODE 0: RoPE. wave covers cols [c0,c0+64) = head dims [0,64) or [64,128)
    _Float16* out = (_Float16*)outp;
    const int sel = (nw >> 6) & 1;  // 0 -> pid row, 1 -> bid row of position_ids
#pragma unroll
    for (int mi = 0; mi < 4; ++mi) {
#pragma unroll
      for (int r = 0; r < 4; ++r) {
        const int row = m0 + mw + mi * 16 + lh * 4 + r;
        const int b = row >> 10, s = row & 1023;
        const int pos = pids[b * 2 * S_ + sel * S_ + s];
#pragma unroll
        for (int ni = 0; ni < 2; ++ni) {
          const int col = n0 + nw + ni * 16 + lr;  // first of (d, d+32) pair
          const int j = ni * 16 + lr;              // 0..31 freq index
          const float c = tcos[pos * 32 + j];
          const float sn = tsin[pos * 32 + j];
          const float x1 = acc[mi][ni][r] + bias[col];
          const float x2 = acc[mi][ni + 2][r] + bias[col + 32];
          const int h = col >> 7, hd = col & 127;
          const size_t base = (((size_t)(b * H_ + h)) * S_ + s) * D_;
          out[base + hd] = (_Float16)(x1 * c - x2 * sn);
          out[base + hd + 32] = (_Float16)(x2 * c + x1 * sn);
        }
      }
    }
  }
}

// ---------------------------------------------------------------------------
// Fused flash attention, 2-phase double-buffered, BT=64, 8 waves/block,
// no P-LDS (in-register redistribution), prev prefetched 1 iteration ahead.
// ---------------------------------------------------------------------------
__global__ __launch_bounds__(512) void flash_kernel(
    const _Float16* __restrict__ q, const _Float16* __restrict__ k,
    const _Float16* __restrict__ vt, const float* __restrict__ pbias,
    const float* __restrict__ maskp, const float* __restrict__ prev,
    float* __restrict__ scores, _Float16* __restrict__ ctx) {
  constexpr int BT = 64;
  __shared__ _Float16 KsBuf[2][BT * D_];   // [t][d] swizzled, 2 x 16 KB
  __shared__ _Float16 VTsBuf[2][D_ * BT];  // [d][t] swizzled, 2 x 16 KB

  const int tid = threadIdx.x, w = tid >> 6, l = tid & 63;
  const int lr = l & 15, lh = l >> 4;
  // XCD swizzle: 512 blocks -> 64 consecutive per XCD (8 planes/XCD)
  const int sid = (blockIdx.x & 7) * 64 + (blockIdx.x >> 3);
  const int qt = sid & 7, byh = sid >> 3;
  const int b = byh >> 4, h = byh & 15;
  const size_t plane = (size_t)byh;
  const int q0 = qt * 128 + w * 16;   // 8 waves x 16 rows = 128 rows/block
  const int qrow = q0 + lr;           // this lane's q-row
  const int swz = (lr & 7) << 3;      // element-index XOR for frag reads

  // P-exchange lane indices (4-lane group, stride 16)
  const int srcA = lr + ((l & 16) << 1);  // lr + 32*(lh&1)
  const int srcB = srcA + 16;
  const bool selHi = (l & 32) != 0;       // lh>>1

  const float* prow  = prev  + (plane * S_ + qrow) * S_;
  const float* pbrow = pbias + ((size_t)h * S_ + qrow) * S_;
  const float* mrow  = maskp + ((size_t)b * S_ + qrow) * S_;
  float*       srow  = scores + (plane * S_ + qrow) * S_;
  const _Float16* kpl = k  + plane * S_ * D_;
  const _Float16* vpl = vt + plane * D_ * S_;

  // Q B-fragments: lane provides Q[row=lr][k]
  f16x8 qa[4];
#pragma unroll
  for (int kk = 0; kk < 4; ++kk)
    qa[kk] = *(const f16x8*)(q + (plane * S_ + qrow) * D_ + kk * 32 + lh * 8);

  f32x4 o[8] = {};
  float m_r = -1e30f, l_r = 0.0f;

  _Float16* ksA = &KsBuf[0][0];
  _Float16* ksB = &KsBuf[1][0];
  _Float16* vtA = &VTsBuf[0][0];
  _Float16* vtB = &VTsBuf[1][0];

  // prologue: stage tile 0 into buffer A; prefetch prev(tile 0)
#pragma unroll
  for (int i = 0; i < 2; ++i) {
    const int e = i * 4096 + tid * 8;
    const int krow = e >> 7;
    gll16(kpl + (size_t)krow * D_ + ((e & 127) ^ ((krow & 7) << 3)), ksA + e);
    const int vrow = e >> 6;
    gll16(vpl + (size_t)vrow * S_ + ((e & 63) ^ ((vrow & 7) << 3)), vtA + e);
  }
  f32x4 pvA[4];
#pragma unroll
  for (int nt = 0; nt < 4; ++nt)
    pvA[nt] = __builtin_nontemporal_load((const f32x4*)(prow + nt * 16 + lh * 4));
  __syncthreads();   // compiler drains vmcnt before s_barrier

  for (int tt = 0; tt < S_ / BT; ++tt) {
    const int t0 = tt * BT;
    const int t1 = (tt < S_ / BT - 1) ? t0 + BT : 0;  // tail wraps, unused

    // pb/mk for THIS tile FIRST (shallow wait in epilogue; L2-resident)
    f32x4 pb4[4], mk4[4];
#pragma unroll
    for (int nt = 0; nt < 4; ++nt) {
      const int toff = t0 + nt * 16 + lh * 4;
      pb4[nt] = *(const f32x4*)(pbrow + toff);
      mk4[nt] = *(const f32x4*)(mrow + toff);
    }
    // prev for NEXT tile (HBM-miss stream; full iteration of cover)
    f32x4 pvB[4];
#pragma unroll
    for (int nt = 0; nt < 4; ++nt)
      pvB[nt] = __builtin_nontemporal_load((const f32x4*)(prow + t1 + nt * 16 + lh * 4));
    // STAGE next K/V tile into the other buffer (async DMA)
    if (tt < S_ / BT - 1) {
#pragma unroll
      for (int i = 0; i < 2; ++i) {
        const int e = i * 4096 + tid * 8;
        const int krow = e >> 7;
        gll16(kpl + (size_t)(t1 + krow) * D_ + ((e & 127) ^ ((krow & 7) << 3)), ksB + e);
        const int vrow = e >> 6;
        gll16(vpl + (size_t)vrow * S_ + t1 + ((e & 63) ^ ((vrow & 7) << 3)), vtB + e);
      }
    }

    // QK^T swapped: sa[nt][r] = S[t = t0+nt*16+lh*4+r][q = qrow]
    f32x4 sa[4] = {};
    __builtin_amdgcn_s_setprio(1);
#pragma unroll
    for (int nt = 0; nt < 4; ++nt)
#pragma unroll
      for (int kk = 0; kk < 4; ++kk) {
        const int row = nt * 16 + lr;
        f16x8 kb = *(const f16x8*)(ksA + row * D_ + ((kk * 32 + lh * 8) ^ swz));
        sa[nt] = MFMA16(kb, qa[kk], sa[nt]);
      }
    __builtin_amdgcn_s_setprio(0);

    // epilogue: score = (qk+pb)/sqrtD + mask + prev(prefetched) ; store
#pragma unroll
    for (int nt = 0; nt < 4; ++nt) {
      const int toff = t0 + nt * 16 + lh * 4;
      f32x4 sc4 = (sa[nt] + pb4[nt]) * RSQRT_D + mk4[nt] + pvA[nt];
      __builtin_nontemporal_store(sc4, (f32x4*)(srow + toff));
      sa[nt] = sc4;
    }

    // online softmax, one q-row per lane; row group = lanes {l, l^16, l^32, l^48}
    float tmx = -1e30f;
#pragma unroll
    for (int nt = 0; nt < 4; ++nt)
#pragma unroll
      for (int r = 0; r < 4; ++r) tmx = fmaxf(tmx, sa[nt][r]);
    tmx = fmaxf(tmx, __shfl_xor(tmx, 16));
    tmx = fmaxf(tmx, __shfl_xor(tmx, 32));
    if (!__all(tmx <= m_r + 8.0f)) {   // T13 defer-max
      const float newm = fmaxf(m_r, tmx);
      const float al = __expf(m_r - newm);
      m_r = newm;
      l_r *= al;
#pragma unroll
      for (int nd = 0; nd < 8; ++nd) o[nd] *= al;
    }
    float ts = 0.0f;
#pragma unroll
    for (int nt = 0; nt < 4; ++nt)
#pragma unroll
      for (int r = 0; r < 4; ++r) {
        const float pe = __expf(sa[nt][r] - m_r);
        sa[nt][r] = pe;
        ts += pe;
      }
    ts += __shfl_xor(ts, 16);
    ts += __shfl_xor(ts, 32);
    l_r += ts;

    // ---- P redistribution in-register (no LDS) ----
    unsigned int u0w0, u0w1, u1w0, u1w1, u2w0, u2w1, u3w0, u3w1;
    {
      f16x4 pk0, pk1, pk2, pk3;
#pragma unroll
      for (int r = 0; r < 4; ++r) {
        pk0[r] = (_Float16)sa[0][r]; pk1[r] = (_Float16)sa[1][r];
        pk2[r] = (_Float16)sa[2][r]; pk3[r] = (_Float16)sa[3][r];
      }
      u32x2 v0 = __builtin_bit_cast(u32x2, pk0); u0w0 = v0[0]; u0w1 = v0[1];
      u32x2 v1 = __builtin_bit_cast(u32x2, pk1); u1w0 = v1[0]; u1w1 = v1[1];
      u32x2 v2 = __builtin_bit_cast(u32x2, pk2); u2w0 = v2[0]; u2w1 = v2[1];
      u32x2 v3 = __builtin_bit_cast(u32x2, pk3); u3w0 = v3[0]; u3w1 = v3[1];
    }
    const unsigned a00 = (unsigned)__shfl((int)u0w0, srcA), a01 = (unsigned)__shfl((int)u0w1, srcA);
    const unsigned a10 = (unsigned)__shfl((int)u1w0, srcA), a11 = (unsigned)__shfl((int)u1w1, srcA);
    const unsigned a20 = (unsigned)__shfl((int)u2w0, srcA), a21 = (unsigned)__shfl((int)u2w1, srcA);
    const unsigned a30 = (unsigned)__shfl((int)u3w0, srcA), a31 = (unsigned)__shfl((int)u3w1, srcA);
    const unsigned b00 = (unsigned)__shfl((int)u0w0, srcB), b01 = (unsigned)__shfl((int)u0w1, srcB);
    const unsigned b10 = (unsigned)__shfl((int)u1w0, srcB), b11 = (unsigned)__shfl((int)u1w1, srcB);
    const unsigned b20 = (unsigned)__shfl((int)u2w0, srcB), b21 = (unsigned)__shfl((int)u2w1, srcB);
    const unsigned b30 = (unsigned)__shfl((int)u3w0, srcB), b31 = (unsigned)__shfl((int)u3w1, srcB);
    u32x4 paw0, paw1;  // pa for kk2=0 (nt 0/1) and kk2=1 (nt 2/3)
    paw0[0] = selHi ? a10 : a00; paw0[1] = selHi ? a11 : a01;
    paw0[2] = selHi ? b10 : b00; paw0[3] = selHi ? b11 : b01;
    paw1[0] = selHi ? a30 : a20; paw1[1] = selHi ? a31 : a21;
    paw1[2] = selHi ? b30 : b20; paw1[3] = selHi ? b31 : b21;
    const f16x8 pa0 = __builtin_bit_cast(f16x8, paw0);
    const f16x8 pa1 = __builtin_bit_cast(f16x8, paw1);

    // PV swapped: o[nd][r] = ctx[d = nd*16+lh*4+r][q = qrow]
    __builtin_amdgcn_s_setprio(1);
#pragma unroll
    for (int nd = 0; nd < 8; ++nd) {
      const int vr = nd * 16 + lr;
      const f16x8 vb0 = *(const f16x8*)(vtA + vr * BT + ((lh * 8) ^ swz));
      o[nd] = MFMA16(vb0, pa0, o[nd]);
    }
#pragma unroll
    for (int nd = 0; nd < 8; ++nd) {
      const int vr = nd * 16 + lr;
      const f16x8 vb1 = *(const f16x8*)(vtA + vr * BT + ((32 + lh * 8) ^ swz));
      o[nd] = MFMA16(vb1, pa1, o[nd]);
    }
    __builtin_amdgcn_s_setprio(0);

    // sole drain point: stage + pvB have had the whole compute phase to land
    __syncthreads();
    _Float16* t1p = ksA; ksA = ksB; ksB = t1p;
    _Float16* t2p = vtA; vtA = vtB; vtB = t2p;
#pragma unroll
    for (int nt = 0; nt < 4; ++nt) pvA[nt] = pvB[nt];
  }

  // ctx write: lane owns q-row qrow, d = nd*16 + lh*4 + r -> f16x4 stores
  const float inv_l = 1.0f / l_r;
  _Float16* crow = ctx + ((size_t)(b * S_) + qrow) * HID_ + h * D_;
#pragma unroll
  for (int nd = 0; nd < 8; ++nd) {
    f16x4 cv;
#pragma unroll
    for (int r = 0; r < 4; ++r) cv[r] = (_Float16)(o[nd][r] * inv_l);
    *(f16x4*)(crow + nd * 16 + lh * 4) = cv;
  }
}

// ---------------------------------------------------------------------------
extern "C" void kernel_launch(void* const* d_in, const int* in_sizes, int n_in,
                              void* d_out, int out_size, void* d_ws, size_t ws_size,
                              hipStream_t stream) {
  const float* query = (const float*)d_in[0];
  const float* key_i = (const float*)d_in[1];
  const float* value = (const float*)d_in[2];
  const float* maskp = (const float*)d_in[3];
  const float* pbias = (const float*)d_in[4];
  const float* prev  = (const float*)d_in[5];
  const int*   pids  = (const int*)d_in[6];
  const float* Wq = (const float*)d_in[7];
  const float* bq = (const float*)d_in[8];
  const float* Wk = (const float*)d_in[9];
  const float* bk = (const float*)d_in[10];
  const float* Wv = (const float*)d_in[11];
  const float* bv = (const float*)d_in[12];
  const float* Wo = (const float*)d_in[13];
  const float* bo = (const float*)d_in[14];

  char* ws = (char*)d_ws;
  // workspace layout (bytes); total need = 134,479,872
  const size_t OFF_TCOS = 0;
  const size_t OFF_TSIN = 131072;
  const size_t OFF_W    = 262144;                      // 4 x 8 MB f16 weights
  const size_t OFF_X    = OFF_W + 4ull * 8388608;      // 3 x 16 MB f16 X
  const size_t OFF_Q    = OFF_X + 3ull * 16777216;
  const size_t OFF_K    = OFF_Q + 16777216;
  const size_t OFF_VT   = OFF_K + 16777216;            // V proj writes here (B,H,D,S)
  const size_t OFF_CTX  = OFF_X + 16777216;            // reuse Xk (consumed)

  float* tcos = (float*)(ws + OFF_TCOS);
  float* tsin = (float*)(ws + OFF_TSIN);
  _Float16* Wq16 = (_Float16*)(ws + OFF_W);
  _Float16* Wk16 = (_Float16*)(ws + OFF_W + 8388608);
  _Float16* Wv16 = (_Float16*)(ws + OFF_W + 2ull * 8388608);
  _Float16* Wo16 = (_Float16*)(ws + OFF_W + 3ull * 8388608);
  _Float16* Xq16 = (_Float16*)(ws + OFF_X);
  _Float16* Xk16 = (_Float16*)(ws + OFF_X + 16777216);
  _Float16* Xv16 = (_Float16*)(ws + OFF_X + 2ull * 16777216);
  _Float16* q16  = (_Float16*)(ws + OFF_Q);
  _Float16* k16  = (_Float16*)(ws + OFF_K);
  _Float16* vt16 = (_Float16*)(ws + OFF_VT);
  _Float16* ctx16 = (_Float16*)(ws + OFF_CTX);

  float* out_f32 = (float*)d_out;                 // (B,S,HID) = 8,388,608
  float* scores  = (float*)d_out + 8388608;       // (B,H,S,S) = 67,108,864

  rope_table_kernel<<<128, 256, 0, stream>>>(tcos, tsin);

  cvt_kernel<<<2048, 256, 0, stream>>>(Wq, Wq16, 524288);
  cvt_kernel<<<2048, 256, 0, stream>>>(Wk, Wk16, 524288);
  cvt_kernel<<<2048, 256, 0, stream>>>(Wv, Wv16, 524288);
  cvt_kernel<<<2048, 256, 0, stream>>>(Wo, Wo16, 524288);
  cvt_kernel<<<4096, 256, 0, stream>>>(query, Xq16, 1048576);
  cvt_kernel<<<4096, 256, 0, stream>>>(key_i, Xk16, 1048576);
  cvt_kernel<<<4096, 256, 0, stream>>>(value, Xv16, 1048576);

  proj_kernel<0><<<512, 256, 0, stream>>>(Xq16, Wq16, bq, (void*)q16, pids, tcos, tsin);
  proj_kernel<0><<<512, 256, 0, stream>>>(Xk16, Wk16, bk, (void*)k16, pids, tcos, tsin);
  proj_kernel<1><<<512, 256, 0, stream>>>(Xv16, Wv16, bv, (void*)vt16, nullptr, nullptr, nullptr);

  flash_kernel<<<512, 512, 0, stream>>>(q16, k16, vt16, pbias, maskp, prev,
                                        scores, ctx16);

  proj_kernel<2><<<512, 256, 0, stream>>>(ctx16, Wo16, bo, (void*)out_f32,
                                          nullptr, nullptr, nullptr);
}

// Round 12
// 460.459 us; speedup vs baseline: 1.0885x; 1.0587x over previous
//
#include <hip/hip_runtime.h>

// ---------------------------------------------------------------------------
// GLMAttention: qkv proj (+RoPE) -> fused flash attn (scores out + softmax+PV)
// -> output proj.  All matmuls fp16 MFMA (16x16x32), f32 accumulate.
// B=4 S=1024 HID=2048 H=16 D=128.
// Round 12: flash reverted to the r7 best (BT=64, 256thr/4 waves, 2-phase
// dbuf, P-LDS, 206us measured). All 7 f32->f16 converts merged into ONE
// segmented kernel (block-uniform segment pick).
// ---------------------------------------------------------------------------

#define B_  4
#define S_  1024
#define HID_ 2048
#define H_  16
#define D_  128
#define RSQRT_D 0.08838834764831845f

typedef _Float16 f16x8 __attribute__((ext_vector_type(8)));
typedef _Float16 f16x4 __attribute__((ext_vector_type(4)));
typedef float f32x4 __attribute__((ext_vector_type(4)));

#define MFMA16(a, b, c) __builtin_amdgcn_mfma_f32_16x16x32_f16(a, b, c, 0, 0, 0)

__device__ __forceinline__ void gll16(const void* g, void* l) {
  __builtin_amdgcn_global_load_lds(
      (const __attribute__((address_space(1))) void*)g,
      (__attribute__((address_space(3))) void*)l, 16, 0, 0);
}

// ---------------------------------------------------------------------------
// RoPE tables: cos/sin[pos][j], j in [0,32), inv_freq = 10000^(-j/32)
// ---------------------------------------------------------------------------
__global__ void rope_table_kernel(float* __restrict__ tcos, float* __restrict__ tsin) {
  int i = blockIdx.x * blockDim.x + threadIdx.x;  // 32768 = 1024*32
  int pos = i >> 5, j = i & 31;
  float inv = expf(-(float)j * (9.210340371976184f / 32.0f));  // ln(10000)/32
  float ang = (float)pos * inv;
  tcos[i] = cosf(ang);
  tsin[i] = sinf(ang);
}

// ---------------------------------------------------------------------------
// Merged f32 -> f16 convert for all 7 tensors, 8 elems/unit.
// Segments: 4 x 524288 (weights) then 3 x 1048576 (X). Every boundary is a
// multiple of 2048 units (one 256-thread block) -> block-uniform branches.
// ---------------------------------------------------------------------------
__global__ __launch_bounds__(256) void cvt_all_kernel(
    const float* __restrict__ w0, const float* __restrict__ w1,
    const float* __restrict__ w2, const float* __restrict__ w3,
    const float* __restrict__ x0, const float* __restrict__ x1,
    const float* __restrict__ x2,
    _Float16* __restrict__ dw0, _Float16* __restrict__ dw1,
    _Float16* __restrict__ dw2, _Float16* __restrict__ dw3,
    _Float16* __restrict__ dx0, _Float16* __restrict__ dx1,
    _Float16* __restrict__ dx2) {
  const int i = blockIdx.x * blockDim.x + threadIdx.x;  // unit index
  const float* src;
  _Float16* dst;
  int off;
  if (i < 2097152) {                 // weights: 4 x 524288
    const int seg = i >> 19;
    off = i & 524287;
    src = (seg == 0) ? w0 : (seg == 1) ? w1 : (seg == 2) ? w2 : w3;
    dst = (seg == 0) ? dw0 : (seg == 1) ? dw1 : (seg == 2) ? dw2 : dw3;
  } else {                           // X: 3 x 1048576
    const int j = i - 2097152;
    const int seg = j >> 20;
    off = j & 1048575;
    src = (seg == 0) ? x0 : (seg == 1) ? x1 : x2;
    dst = (seg == 0) ? dx0 : (seg == 1) ? dx1 : dx2;
  }
  const f32x4* in4 = (const f32x4*)src;
  f32x4 a = in4[(size_t)off * 2], b = in4[(size_t)off * 2 + 1];
  f16x8 v;
  v[0] = (_Float16)a[0]; v[1] = (_Float16)a[1]; v[2] = (_Float16)a[2]; v[3] = (_Float16)a[3];
  v[4] = (_Float16)b[0]; v[5] = (_Float16)b[1]; v[6] = (_Float16)b[2]; v[7] = (_Float16)b[3];
  *(f16x8*)(dst + (size_t)off * 8) = v;
}

// ---------------------------------------------------------------------------
// GEMM: C = A(MxK) @ W(NxK)^T + bias.  128x128 tile, BK=64, 4 waves, 4x4 frags.
// MODE 0: RoPE epilogue  -> f16 out (B,H,S,D)
// MODE 1: V head, transposed -> f16 out (B,H,D,S)
// MODE 2: f32 + bias     -> f32 out (M,N)  (final output)
// ---------------------------------------------------------------------------
template <int MODE>
__global__ __launch_bounds__(256) void proj_kernel(
    const _Float16* __restrict__ A, const _Float16* __restrict__ Bw,
    const float* __restrict__ bias, void* __restrict__ outp,
    const int* __restrict__ pids, const float* __restrict__ tcos,
    const float* __restrict__ tsin) {
  constexpr int N = HID_, K = HID_;
  constexpr int BK = 64;
  __shared__ _Float16 As[128 * BK];
  __shared__ _Float16 Bs[128 * BK];

  const int tid = threadIdx.x;
  // XCD-aware swizzle (512 blocks, 512%8==0 -> bijective)
  const int bid = (blockIdx.x & 7) * 64 + (blockIdx.x >> 3);
  const int tm = bid >> 4, tn = bid & 15;  // 32 x 16 tiles
  const int m0 = tm * 128, n0 = tn * 128;
  const int w = tid >> 6, l = tid & 63;
  const int mw = (w >> 1) * 64, nw = (w & 1) * 64;
  const int lr = l & 15, lh = l >> 4;

  f32x4 acc[4][4] = {};

  for (int kt = 0; kt < K / BK; ++kt) {
    const int k0 = kt * BK;
    __syncthreads();
#pragma unroll
    for (int i = 0; i < 4; ++i) {
      const int e = i * 2048 + tid * 8;
      gll16(A + (size_t)(m0 + (e >> 6)) * K + k0 + (e & 63), As + e);
      gll16(Bw + (size_t)(n0 + (e >> 6)) * K + k0 + (e & 63), Bs + e);
    }
    asm volatile("s_waitcnt vmcnt(0)" ::: "memory");
    __syncthreads();
#pragma unroll
    for (int kk = 0; kk < 2; ++kk) {
      f16x8 af[4], bf[4];
#pragma unroll
      for (int mi = 0; mi < 4; ++mi)
        af[mi] = *(const f16x8*)(As + (mw + mi * 16 + lr) * BK + kk * 32 + lh * 8);
#pragma unroll
      for (int ni = 0; ni < 4; ++ni)
        bf[ni] = *(const f16x8*)(Bs + (nw + ni * 16 + lr) * BK + kk * 32 + lh * 8);
#pragma unroll
      for (int mi = 0; mi < 4; ++mi)
#pragma unroll
        for (int ni = 0; ni < 4; ++ni)
          acc[mi][ni] = MFMA16(af[mi], bf[ni], acc[mi][ni]);
    }
  }

  if constexpr (MODE == 2) {
    float* out = (float*)outp;
#pragma unroll
    for (int mi = 0; mi < 4; ++mi)
#pragma unroll
      for (int ni = 0; ni < 4; ++ni) {
        const int col = n0 + nw + ni * 16 + lr;
        const float bb = bias[col];
#pragma unroll
        for (int r = 0; r < 4; ++r) {
          const int row = m0 + mw + mi * 16 + lh * 4 + r;
          out[(size_t)row * N + col] = acc[mi][ni][r] + bb;
        }
      }
  } else if constexpr (MODE == 1) {  // V: write (B,H,D,S) directly
    _Float16* out = (_Float16*)outp;
#pragma unroll
    for (int mi = 0; mi < 4; ++mi)
#pragma unroll
      for (int ni = 0; ni < 4; ++ni) {
        const int col = n0 + nw + ni * 16 + lr;
        const float bb = bias[col];
        const int h = col >> 7, hd = col & 127;
#pragma unroll
        for (int r = 0; r < 4; ++r) {
          const int row = m0 + mw + mi * 16 + lh * 4 + r;
          const int b = row >> 10, s = row & 1023;
          out[(((size_t)(b * H_ + h)) * D_ + hd) * S_ + s] = (_Float16)(acc[mi][ni][r] + bb);
        }
      }
  } else {  // MODE 0: RoPE. wave covers cols [c0,c0+64) = head dims [0,64) or [64,128)
    _Float16* out = (_Float16*)outp;
    const int sel = (nw >> 6) & 1;  // 0 -> pid row, 1 -> bid row of position_ids
#pragma unroll
    for (int mi = 0; mi < 4; ++mi) {
#pragma unroll
      for (int r = 0; r < 4; ++r) {
        const int row = m0 + mw + mi * 16 + lh * 4 + r;
        const int b = row >> 10, s = row & 1023;
        const int pos = pids[b * 2 * S_ + sel * S_ + s];
#pragma unroll
        for (int ni = 0; ni < 2; ++ni) {
          const int col = n0 + nw + ni * 16 + lr;  // first of (d, d+32) pair
          const int j = ni * 16 + lr;              // 0..31 freq index
          const float c = tcos[pos * 32 + j];
          const float sn = tsin[pos * 32 + j];
          const float x1 = acc[mi][ni][r] + bias[col];
          const float x2 = acc[mi][ni + 2][r] + bias[col + 32];
          const int h = col >> 7, hd = col & 127;
          const size_t base = (((size_t)(b * H_ + h)) * S_ + s) * D_;
          out[base + hd] = (_Float16)(x1 * c - x2 * sn);
          out[base + hd + 32] = (_Float16)(x2 * c + x1 * sn);
        }
      }
    }
  }
}

// ---------------------------------------------------------------------------
// Fused flash attention, 2-phase double-buffered (r7 best config).
// Block = (b,h, 64 q-rows); 4 waves x 16 rows. Swapped MFMA operands
// (S layout [t][q], o layout [d][q]); LDS XOR-swizzled via pre-swizzled
// global_load_lds source. Per iteration: issue streams(t), issue STAGE(t+1)
// into the other buffer, compute(t), __syncthreads (sole drain), swap.
// ---------------------------------------------------------------------------
__global__ __launch_bounds__(256) void flash_kernel(
    const _Float16* __restrict__ q, const _Float16* __restrict__ k,
    const _Float16* __restrict__ vt, const float* __restrict__ pbias,
    const float* __restrict__ maskp, const float* __restrict__ prev,
    float* __restrict__ scores, _Float16* __restrict__ ctx) {
  constexpr int BT = 64;
  __shared__ _Float16 KsBuf[2][BT * D_];   // [t][d] swizzled, 2 x 16 KB
  __shared__ _Float16 VTsBuf[2][D_ * BT];  // [d][t] swizzled, 2 x 16 KB
  __shared__ _Float16 Ps[4][16 * BT];      // per-wave [q][t] swizzled, 8 KB

  const int tid = threadIdx.x, w = tid >> 6, l = tid & 63;
  const int lr = l & 15, lh = l >> 4;
  // XCD swizzle: 1024 blocks -> 128 consecutive per XCD (8 planes/XCD)
  const int sid = (blockIdx.x & 7) * 128 + (blockIdx.x >> 3);
  const int qt = sid & 15, byh = sid >> 4;
  const int b = byh >> 4, h = byh & 15;
  const size_t plane = (size_t)byh;
  const int q0 = qt * 64 + w * 16;
  const int qrow = q0 + lr;           // this lane's q-row
  const int swz = (lr & 7) << 3;      // element-index XOR for frag reads

  const float* prow  = prev  + (plane * S_ + qrow) * S_;
  const float* pbrow = pbias + ((size_t)h * S_ + qrow) * S_;
  const float* mrow  = maskp + ((size_t)b * S_ + qrow) * S_;
  float*       srow  = scores + (plane * S_ + qrow) * S_;
  const _Float16* kpl = k  + plane * S_ * D_;
  const _Float16* vpl = vt + plane * D_ * S_;

  // Q B-fragments: lane provides Q[row=lr][k]
  f16x8 qa[4];
#pragma unroll
  for (int kk = 0; kk < 4; ++kk)
    qa[kk] = *(const f16x8*)(q + (plane * S_ + qrow) * D_ + kk * 32 + lh * 8);

  f32x4 o[8] = {};
  float m_r = -1e30f, l_r = 0.0f;

  _Float16* ksA = &KsBuf[0][0];
  _Float16* ksB = &KsBuf[1][0];
  _Float16* vtA = &VTsBuf[0][0];
  _Float16* vtB = &VTsBuf[1][0];

  // prologue: stage tile 0 into buffer A
#pragma unroll
  for (int i = 0; i < 4; ++i) {
    const int e = i * 2048 + tid * 8;
    const int krow = e >> 7;
    gll16(kpl + (size_t)krow * D_ + ((e & 127) ^ ((krow & 7) << 3)), ksA + e);
    const int vrow = e >> 6;
    gll16(vpl + (size_t)vrow * S_ + ((e & 63) ^ ((vrow & 7) << 3)), vtA + e);
  }
  __syncthreads();   // compiler drains vmcnt before s_barrier

  for (int tt = 0; tt < S_ / BT; ++tt) {
    const int t0 = tt * BT;

    // streams for THIS tile (needed after QK^T; deepest-issued)
    f32x4 pv4[4], pb4[4], mk4[4];
#pragma unroll
    for (int nt = 0; nt < 4; ++nt) {
      const int toff = t0 + nt * 16 + lh * 4;
      pv4[nt] = __builtin_nontemporal_load((const f32x4*)(prow + toff));
      pb4[nt] = *(const f32x4*)(pbrow + toff);
      mk4[nt] = *(const f32x4*)(mrow + toff);
    }
    // STAGE next tile into the other buffer (async DMA, drained at the
    // end-of-iteration barrier after the whole compute phase)
    if (tt < S_ / BT - 1) {
      const int t1 = t0 + BT;
#pragma unroll
      for (int i = 0; i < 4; ++i) {
        const int e = i * 2048 + tid * 8;
        const int krow = e >> 7;
        gll16(kpl + (size_t)(t1 + krow) * D_ + ((e & 127) ^ ((krow & 7) << 3)), ksB + e);
        const int vrow = e >> 6;
        gll16(vpl + (size_t)vrow * S_ + t1 + ((e & 63) ^ ((vrow & 7) << 3)), vtB + e);
      }
    }

    // QK^T swapped: sa[nt][r] = S[t = t0+nt*16+lh*4+r][q = qrow]
    f32x4 sa[4] = {};
    __builtin_amdgcn_s_setprio(1);
#pragma unroll
    for (int nt = 0; nt < 4; ++nt)
#pragma unroll
      for (int kk = 0; kk < 4; ++kk) {
        const int row = nt * 16 + lr;
        f16x8 kb = *(const f16x8*)(ksA + row * D_ + ((kk * 32 + lh * 8) ^ swz));
        sa[nt] = MFMA16(kb, qa[kk], sa[nt]);
      }
    __builtin_amdgcn_s_setprio(0);

    // epilogue: score = (qk+pb)/sqrtD + mask + prev ; pure VALU + store
#pragma unroll
    for (int nt = 0; nt < 4; ++nt) {
      const int toff = t0 + nt * 16 + lh * 4;
      f32x4 sc4 = (sa[nt] + pb4[nt]) * RSQRT_D + mk4[nt] + pv4[nt];
      __builtin_nontemporal_store(sc4, (f32x4*)(srow + toff));
      sa[nt] = sc4;
    }

    // online softmax, one q-row per lane; row group = lanes {l, l^16, l^32, l^48}
    float tmx = -1e30f;
#pragma unroll
    for (int nt = 0; nt < 4; ++nt)
#pragma unroll
      for (int r = 0; r < 4; ++r) tmx = fmaxf(tmx, sa[nt][r]);
    tmx = fmaxf(tmx, __shfl_xor(tmx, 16));
    tmx = fmaxf(tmx, __shfl_xor(tmx, 32));
    if (!__all(tmx <= m_r + 8.0f)) {   // T13 defer-max
      const float newm = fmaxf(m_r, tmx);
      const float al = __expf(m_r - newm);
      m_r = newm;
      l_r *= al;
#pragma unroll
      for (int nd = 0; nd < 8; ++nd) o[nd] *= al;
    }
    float ts = 0.0f;
#pragma unroll
    for (int nt = 0; nt < 4; ++nt)
#pragma unroll
      for (int r = 0; r < 4; ++r) {
        const float pe = __expf(sa[nt][r] - m_r);
        sa[nt][r] = pe;
        ts += pe;
      }
    ts += __shfl_xor(ts, 16);
    ts += __shfl_xor(ts, 32);
    l_r += ts;

    // P -> per-wave LDS [q=lr][t], swizzled, f16x4 stores (wave-local)
    _Float16* pw = &Ps[w][0];
#pragma unroll
    for (int nt = 0; nt < 4; ++nt) {
      f16x4 pk;
      pk[0] = (_Float16)sa[nt][0]; pk[1] = (_Float16)sa[nt][1];
      pk[2] = (_Float16)sa[nt][2]; pk[3] = (_Float16)sa[nt][3];
      *(f16x4*)(pw + lr * BT + ((nt * 16 + lh * 4) ^ swz)) = pk;
    }

    // PV swapped: o[nd][r] = ctx[d = nd*16+lh*4+r][q = qrow]
    __builtin_amdgcn_s_setprio(1);
#pragma unroll
    for (int kk2 = 0; kk2 < 2; ++kk2) {
      const f16x8 pa = *(const f16x8*)(pw + lr * BT + ((kk2 * 32 + lh * 8) ^ swz));
#pragma unroll
      for (int nd = 0; nd < 8; ++nd) {
        const int vr = nd * 16 + lr;
        const f16x8 vb = *(const f16x8*)(vtA + vr * BT + ((kk2 * 32 + lh * 8) ^ swz));
        o[nd] = MFMA16(vb, pa, o[nd]);
      }
    }
    __builtin_amdgcn_s_setprio(0);

    // sole drain point: waits this wave's gll16s + stores, then barrier
    __syncthreads();
    _Float16* t1p = ksA; ksA = ksB; ksB = t1p;
    _Float16* t2p = vtA; vtA = vtB; vtB = t2p;
  }

  // ctx write: lane owns q-row qrow, d = nd*16 + lh*4 + r -> f16x4 stores
  const float inv_l = 1.0f / l_r;
  _Float16* crow = ctx + ((size_t)(b * S_) + qrow) * HID_ + h * D_;
#pragma unroll
  for (int nd = 0; nd < 8; ++nd) {
    f16x4 cv;
#pragma unroll
    for (int r = 0; r < 4; ++r) cv[r] = (_Float16)(o[nd][r] * inv_l);
    *(f16x4*)(crow + nd * 16 + lh * 4) = cv;
  }
}

// ---------------------------------------------------------------------------
extern "C" void kernel_launch(void* const* d_in, const int* in_sizes, int n_in,
                              void* d_out, int out_size, void* d_ws, size_t ws_size,
                              hipStream_t stream) {
  const float* query = (const float*)d_in[0];
  const float* key_i = (const float*)d_in[1];
  const float* value = (const float*)d_in[2];
  const float* maskp = (const float*)d_in[3];
  const float* pbias = (const float*)d_in[4];
  const float* prev  = (const float*)d_in[5];
  const int*   pids  = (const int*)d_in[6];
  const float* Wq = (const float*)d_in[7];
  const float* bq = (const float*)d_in[8];
  const float* Wk = (const float*)d_in[9];
  const float* bk = (const float*)d_in[10];
  const float* Wv = (const float*)d_in[11];
  const float* bv = (const float*)d_in[12];
  const float* Wo = (const float*)d_in[13];
  const float* bo = (const float*)d_in[14];

  char* ws = (char*)d_ws;
  // workspace layout (bytes); total need = 134,479,872
  const size_t OFF_TCOS = 0;
  const size_t OFF_TSIN = 131072;
  const size_t OFF_W    = 262144;                      // 4 x 8 MB f16 weights
  const size_t OFF_X    = OFF_W + 4ull * 8388608;      // 3 x 16 MB f16 X
  const size_t OFF_Q    = OFF_X + 3ull * 16777216;
  const size_t OFF_K    = OFF_Q + 16777216;
  const size_t OFF_VT   = OFF_K + 16777216;            // V proj writes here (B,H,D,S)
  const size_t OFF_CTX  = OFF_X + 16777216;            // reuse Xk (consumed)

  float* tcos = (float*)(ws + OFF_TCOS);
  float* tsin = (float*)(ws + OFF_TSIN);
  _Float16* Wq16 = (_Float16*)(ws + OFF_W);
  _Float16* Wk16 = (_Float16*)(ws + OFF_W + 8388608);
  _Float16* Wv16 = (_Float16*)(ws + OFF_W + 2ull * 8388608);
  _Float16* Wo16 = (_Float16*)(ws + OFF_W + 3ull * 8388608);
  _Float16* Xq16 = (_Float16*)(ws + OFF_X);
  _Float16* Xk16 = (_Float16*)(ws + OFF_X + 16777216);
  _Float16* Xv16 = (_Float16*)(ws + OFF_X + 2ull * 16777216);
  _Float16* q16  = (_Float16*)(ws + OFF_Q);
  _Float16* k16  = (_Float16*)(ws + OFF_K);
  _Float16* vt16 = (_Float16*)(ws + OFF_VT);
  _Float16* ctx16 = (_Float16*)(ws + OFF_CTX);

  float* out_f32 = (float*)d_out;                 // (B,S,HID) = 8,388,608
  float* scores  = (float*)d_out + 8388608;       // (B,H,S,S) = 67,108,864

  rope_table_kernel<<<128, 256, 0, stream>>>(tcos, tsin);

  // one merged convert: 4 weights + 3 X tensors (5,242,880 units / 256)
  cvt_all_kernel<<<20480, 256, 0, stream>>>(Wq, Wk, Wv, Wo, query, key_i, value,
                                            Wq16, Wk16, Wv16, Wo16,
                                            Xq16, Xk16, Xv16);

  proj_kernel<0><<<512, 256, 0, stream>>>(Xq16, Wq16, bq, (void*)q16, pids, tcos, tsin);
  proj_kernel<0><<<512, 256, 0, stream>>>(Xk16, Wk16, bk, (void*)k16, pids, tcos, tsin);
  proj_kernel<1><<<512, 256, 0, stream>>>(Xv16, Wv16, bv, (void*)vt16, nullptr, nullptr, nullptr);

  flash_kernel<<<1024, 256, 0, stream>>>(q16, k16, vt16, pbias, maskp, prev,
                                         scores, ctx16);

  proj_kernel<2><<<512, 256, 0, stream>>>(ctx16, Wo16, bo, (void*)out_f32,
                                          nullptr, nullptr, nullptr);
}

// Round 13
// 455.222 us; speedup vs baseline: 1.1010x; 1.0115x over previous
//
#include <hip/hip_runtime.h>

// ---------------------------------------------------------------------------
// GLMAttention: qkv proj (+RoPE) -> fused flash attn (scores out + softmax+PV)
// -> output proj.  All matmuls fp16 MFMA (16x16x32), f32 accumulate.
// B=4 S=1024 HID=2048 H=16 D=128.
// Round 13: the 3 input projections fused into ONE 1536-block launch
// (segmented; one drain tail instead of three); rope table folded into the
// cvt launch. Flash = r7 best (206us). Final proj unchanged.
// ---------------------------------------------------------------------------

#define B_  4
#define S_  1024
#define HID_ 2048
#define H_  16
#define D_  128
#define RSQRT_D 0.08838834764831845f

typedef _Float16 f16x8 __attribute__((ext_vector_type(8)));
typedef _Float16 f16x4 __attribute__((ext_vector_type(4)));
typedef float f32x4 __attribute__((ext_vector_type(4)));

#define MFMA16(a, b, c) __builtin_amdgcn_mfma_f32_16x16x32_f16(a, b, c, 0, 0, 0)

__device__ __forceinline__ void gll16(const void* g, void* l) {
  __builtin_amdgcn_global_load_lds(
      (const __attribute__((address_space(1))) void*)g,
      (__attribute__((address_space(3))) void*)l, 16, 0, 0);
}

// ---------------------------------------------------------------------------
// Merged f32 -> f16 convert for all 7 tensors + RoPE tables.
// Blocks [0, 20480): convert (8 elems/thread). Blocks [20480, 20608): tables.
// ---------------------------------------------------------------------------
__global__ __launch_bounds__(256) void cvt_all_kernel(
    const float* __restrict__ w0, const float* __restrict__ w1,
    const float* __restrict__ w2, const float* __restrict__ w3,
    const float* __restrict__ x0, const float* __restrict__ x1,
    const float* __restrict__ x2,
    _Float16* __restrict__ dw0, _Float16* __restrict__ dw1,
    _Float16* __restrict__ dw2, _Float16* __restrict__ dw3,
    _Float16* __restrict__ dx0, _Float16* __restrict__ dx1,
    _Float16* __restrict__ dx2,
    float* __restrict__ tcos, float* __restrict__ tsin) {
  if (blockIdx.x >= 20480) {  // RoPE tables: 32768 entries
    const int i = (blockIdx.x - 20480) * 256 + threadIdx.x;
    const int pos = i >> 5, j = i & 31;
    const float inv = expf(-(float)j * (9.210340371976184f / 32.0f));
    const float ang = (float)pos * inv;
    tcos[i] = cosf(ang);
    tsin[i] = sinf(ang);
    return;
  }
  const int i = blockIdx.x * blockDim.x + threadIdx.x;  // unit index
  const float* src;
  _Float16* dst;
  int off;
  if (i < 2097152) {                 // weights: 4 x 524288
    const int seg = i >> 19;
    off = i & 524287;
    src = (seg == 0) ? w0 : (seg == 1) ? w1 : (seg == 2) ? w2 : w3;
    dst = (seg == 0) ? dw0 : (seg == 1) ? dw1 : (seg == 2) ? dw2 : dw3;
  } else {                           // X: 3 x 1048576
    const int j = i - 2097152;
    const int seg = j >> 20;
    off = j & 1048575;
    src = (seg == 0) ? x0 : (seg == 1) ? x1 : x2;
    dst = (seg == 0) ? dx0 : (seg == 1) ? dx1 : dx2;
  }
  const f32x4* in4 = (const f32x4*)src;
  f32x4 a = in4[(size_t)off * 2], b = in4[(size_t)off * 2 + 1];
  f16x8 v;
  v[0] = (_Float16)a[0]; v[1] = (_Float16)a[1]; v[2] = (_Float16)a[2]; v[3] = (_Float16)a[3];
  v[4] = (_Float16)b[0]; v[5] = (_Float16)b[1]; v[6] = (_Float16)b[2]; v[7] = (_Float16)b[3];
  *(f16x8*)(dst + (size_t)off * 8) = v;
}

// ---------------------------------------------------------------------------
// Fused Q/K/V projection: one 1536-block launch, 512 blocks per segment.
// C = A(MxK) @ W(NxK)^T + bias; seg 0/1 -> RoPE epilogue (B,H,S,D);
// seg 2 (V) -> transposed head epilogue (B,H,D,S).
// 128x128 tile, BK=64, 4 waves, 4x4 frags; global XCD swizzle (1536%8==0).
// ---------------------------------------------------------------------------
__global__ __launch_bounds__(256) void proj_qkv_kernel(
    const _Float16* __restrict__ Xq, const _Float16* __restrict__ Xk,
    const _Float16* __restrict__ Xv,
    const _Float16* __restrict__ Wq, const _Float16* __restrict__ Wk,
    const _Float16* __restrict__ Wv,
    const float* __restrict__ bq, const float* __restrict__ bk,
    const float* __restrict__ bv,
    _Float16* __restrict__ oq, _Float16* __restrict__ ok,
    _Float16* __restrict__ ovt,
    const int* __restrict__ pids, const float* __restrict__ tcos,
    const float* __restrict__ tsin) {
  constexpr int N = HID_, K = HID_;
  constexpr int BK = 64;
  __shared__ _Float16 As[128 * BK];
  __shared__ _Float16 Bs[128 * BK];

  const int tid = threadIdx.x;
  // XCD-aware swizzle over the full 1536-block grid (1536%8==0 -> bijective)
  const int gbid = (blockIdx.x & 7) * 192 + (blockIdx.x >> 3);
  const int seg = gbid >> 9;          // 0=q, 1=k, 2=v (block-uniform)
  const int bid = gbid & 511;
  const _Float16* A  = (seg == 0) ? Xq : (seg == 1) ? Xk : Xv;
  const _Float16* Bw = (seg == 0) ? Wq : (seg == 1) ? Wk : Wv;
  const float*  bias = (seg == 0) ? bq : (seg == 1) ? bk : bv;

  const int tm = bid >> 4, tn = bid & 15;  // 32 x 16 tiles
  const int m0 = tm * 128, n0 = tn * 128;
  const int w = tid >> 6, l = tid & 63;
  const int mw = (w >> 1) * 64, nw = (w & 1) * 64;
  const int lr = l & 15, lh = l >> 4;

  f32x4 acc[4][4] = {};

  for (int kt = 0; kt < K / BK; ++kt) {
    const int k0 = kt * BK;
    __syncthreads();
#pragma unroll
    for (int i = 0; i < 4; ++i) {
      const int e = i * 2048 + tid * 8;
      gll16(A + (size_t)(m0 + (e >> 6)) * K + k0 + (e & 63), As + e);
      gll16(Bw + (size_t)(n0 + (e >> 6)) * K + k0 + (e & 63), Bs + e);
    }
    asm volatile("s_waitcnt vmcnt(0)" ::: "memory");
    __syncthreads();
#pragma unroll
    for (int kk = 0; kk < 2; ++kk) {
      f16x8 af[4], bf[4];
#pragma unroll
      for (int mi = 0; mi < 4; ++mi)
        af[mi] = *(const f16x8*)(As + (mw + mi * 16 + lr) * BK + kk * 32 + lh * 8);
#pragma unroll
      for (int ni = 0; ni < 4; ++ni)
        bf[ni] = *(const f16x8*)(Bs + (nw + ni * 16 + lr) * BK + kk * 32 + lh * 8);
#pragma unroll
      for (int mi = 0; mi < 4; ++mi)
#pragma unroll
        for (int ni = 0; ni < 4; ++ni)
          acc[mi][ni] = MFMA16(af[mi], bf[ni], acc[mi][ni]);
    }
  }

  if (seg == 2) {  // V: write (B,H,D,S) directly
    _Float16* out = ovt;
#pragma unroll
    for (int mi = 0; mi < 4; ++mi)
#pragma unroll
      for (int ni = 0; ni < 4; ++ni) {
        const int col = n0 + nw + ni * 16 + lr;
        const float bb = bias[col];
        const int h = col >> 7, hd = col & 127;
#pragma unroll
        for (int r = 0; r < 4; ++r) {
          const int row = m0 + mw + mi * 16 + lh * 4 + r;
          const int b = row >> 10, s = row & 1023;
          out[(((size_t)(b * H_ + h)) * D_ + hd) * S_ + s] = (_Float16)(acc[mi][ni][r] + bb);
        }
      }
  } else {  // q/k: RoPE epilogue. wave covers cols = head dims [0,64) or [64,128)
    _Float16* out = (seg == 0) ? oq : ok;
    const int sel = (nw >> 6) & 1;  // 0 -> pid row, 1 -> bid row of position_ids
#pragma unroll
    for (int mi = 0; mi < 4; ++mi) {
#pragma unroll
      for (int r = 0; r < 4; ++r) {
        const int row = m0 + mw + mi * 16 + lh * 4 + r;
        const int b = row >> 10, s = row & 1023;
        const int pos = pids[b * 2 * S_ + sel * S_ + s];
#pragma unroll
        for (int ni = 0; ni < 2; ++ni) {
          const int col = n0 + nw + ni * 16 + lr;  // first of (d, d+32) pair
          const int j = ni * 16 + lr;              // 0..31 freq index
          const float c = tcos[pos * 32 + j];
          const float sn = tsin[pos * 32 + j];
          const float x1 = acc[mi][ni][r] + bias[col];
          const float x2 = acc[mi][ni + 2][r] + bias[col + 32];
          const int h = col >> 7, hd = col & 127;
          const size_t base = (((size_t)(b * H_ + h)) * S_ + s) * D_;
          out[base + hd] = (_Float16)(x1 * c - x2 * sn);
          out[base + hd + 32] = (_Float16)(x2 * c + x1 * sn);
        }
      }
    }
  }
}

// ---------------------------------------------------------------------------
// Final projection: C = ctx @ Wo^T + bo -> f32 (M,N).
// ---------------------------------------------------------------------------
__global__ __launch_bounds__(256) void proj_out_kernel(
    const _Float16* __restrict__ A, const _Float16* __restrict__ Bw,
    const float* __restrict__ bias, float* __restrict__ out) {
  constexpr int N = HID_, K = HID_;
  constexpr int BK = 64;
  __shared__ _Float16 As[128 * BK];
  __shared__ _Float16 Bs[128 * BK];

  const int tid = threadIdx.x;
  const int bid = (blockIdx.x & 7) * 64 + (blockIdx.x >> 3);
  const int tm = bid >> 4, tn = bid & 15;
  const int m0 = tm * 128, n0 = tn * 128;
  const int w = tid >> 6, l = tid & 63;
  const int mw = (w >> 1) * 64, nw = (w & 1) * 64;
  const int lr = l & 15, lh = l >> 4;

  f32x4 acc[4][4] = {};

  for (int kt = 0; kt < K / BK; ++kt) {
    const int k0 = kt * BK;
    __syncthreads();
#pragma unroll
    for (int i = 0; i < 4; ++i) {
      const int e = i * 2048 + tid * 8;
      gll16(A + (size_t)(m0 + (e >> 6)) * K + k0 + (e & 63), As + e);
      gll16(Bw + (size_t)(n0 + (e >> 6)) * K + k0 + (e & 63), Bs + e);
    }
    asm volatile("s_waitcnt vmcnt(0)" ::: "memory");
    __syncthreads();
#pragma unroll
    for (int kk = 0; kk < 2; ++kk) {
      f16x8 af[4], bf[4];
#pragma unroll
      for (int mi = 0; mi < 4; ++mi)
        af[mi] = *(const f16x8*)(As + (mw + mi * 16 + lr) * BK + kk * 32 + lh * 8);
#pragma unroll
      for (int ni = 0; ni < 4; ++ni)
        bf[ni] = *(const f16x8*)(Bs + (nw + ni * 16 + lr) * BK + kk * 32 + lh * 8);
#pragma unroll
      for (int mi = 0; mi < 4; ++mi)
#pragma unroll
        for (int ni = 0; ni < 4; ++ni)
          acc[mi][ni] = MFMA16(af[mi], bf[ni], acc[mi][ni]);
    }
  }

#pragma unroll
  for (int mi = 0; mi < 4; ++mi)
#pragma unroll
    for (int ni = 0; ni < 4; ++ni) {
      const int col = n0 + nw + ni * 16 + lr;
      const float bb = bias[col];
#pragma unroll
      for (int r = 0; r < 4; ++r) {
        const int row = m0 + mw + mi * 16 + lh * 4 + r;
        out[(size_t)row * N + col] = acc[mi][ni][r] + bb;
      }
    }
}

// ---------------------------------------------------------------------------
// Fused flash attention, 2-phase double-buffered (r7 best config, 206us).
// Block = (b,h, 64 q-rows); 4 waves x 16 rows. Swapped MFMA operands
// (S layout [t][q], o layout [d][q]); LDS XOR-swizzled via pre-swizzled
// global_load_lds source. Per iteration: issue streams(t), issue STAGE(t+1)
// into the other buffer, compute(t), __syncthreads (sole drain), swap.
// ---------------------------------------------------------------------------
__global__ __launch_bounds__(256) void flash_kernel(
    const _Float16* __restrict__ q, const _Float16* __restrict__ k,
    const _Float16* __restrict__ vt, const float* __restrict__ pbias,
    const float* __restrict__ maskp, const float* __restrict__ prev,
    float* __restrict__ scores, _Float16* __restrict__ ctx) {
  constexpr int BT = 64;
  __shared__ _Float16 KsBuf[2][BT * D_];   // [t][d] swizzled, 2 x 16 KB
  __shared__ _Float16 VTsBuf[2][D_ * BT];  // [d][t] swizzled, 2 x 16 KB
  __shared__ _Float16 Ps[4][16 * BT];      // per-wave [q][t] swizzled, 8 KB

  const int tid = threadIdx.x, w = tid >> 6, l = tid & 63;
  const int lr = l & 15, lh = l >> 4;
  // XCD swizzle: 1024 blocks -> 128 consecutive per XCD (8 planes/XCD)
  const int sid = (blockIdx.x & 7) * 128 + (blockIdx.x >> 3);
  const int qt = sid & 15, byh = sid >> 4;
  const int b = byh >> 4, h = byh & 15;
  const size_t plane = (size_t)byh;
  const int q0 = qt * 64 + w * 16;
  const int qrow = q0 + lr;           // this lane's q-row
  const int swz = (lr & 7) << 3;      // element-index XOR for frag reads

  const float* prow  = prev  + (plane * S_ + qrow) * S_;
  const float* pbrow = pbias + ((size_t)h * S_ + qrow) * S_;
  const float* mrow  = maskp + ((size_t)b * S_ + qrow) * S_;
  float*       srow  = scores + (plane * S_ + qrow) * S_;
  const _Float16* kpl = k  + plane * S_ * D_;
  const _Float16* vpl = vt + plane * D_ * S_;

  // Q B-fragments: lane provides Q[row=lr][k]
  f16x8 qa[4];
#pragma unroll
  for (int kk = 0; kk < 4; ++kk)
    qa[kk] = *(const f16x8*)(q + (plane * S_ + qrow) * D_ + kk * 32 + lh * 8);

  f32x4 o[8] = {};
  float m_r = -1e30f, l_r = 0.0f;

  _Float16* ksA = &KsBuf[0][0];
  _Float16* ksB = &KsBuf[1][0];
  _Float16* vtA = &VTsBuf[0][0];
  _Float16* vtB = &VTsBuf[1][0];

  // prologue: stage tile 0 into buffer A
#pragma unroll
  for (int i = 0; i < 4; ++i) {
    const int e = i * 2048 + tid * 8;
    const int krow = e >> 7;
    gll16(kpl + (size_t)krow * D_ + ((e & 127) ^ ((krow & 7) << 3)), ksA + e);
    const int vrow = e >> 6;
    gll16(vpl + (size_t)vrow * S_ + ((e & 63) ^ ((vrow & 7) << 3)), vtA + e);
  }
  __syncthreads();   // compiler drains vmcnt before s_barrier

  for (int tt = 0; tt < S_ / BT; ++tt) {
    const int t0 = tt * BT;

    // streams for THIS tile (needed after QK^T; deepest-issued)
    f32x4 pv4[4], pb4[4], mk4[4];
#pragma unroll
    for (int nt = 0; nt < 4; ++nt) {
      const int toff = t0 + nt * 16 + lh * 4;
      pv4[nt] = __builtin_nontemporal_load((const f32x4*)(prow + toff));
      pb4[nt] = *(const f32x4*)(pbrow + toff);
      mk4[nt] = *(const f32x4*)(mrow + toff);
    }
    // STAGE next tile into the other buffer (async DMA, drained at the
    // end-of-iteration barrier after the whole compute phase)
    if (tt < S_ / BT - 1) {
      const int t1 = t0 + BT;
#pragma unroll
      for (int i = 0; i < 4; ++i) {
        const int e = i * 2048 + tid * 8;
        const int krow = e >> 7;
        gll16(kpl + (size_t)(t1 + krow) * D_ + ((e & 127) ^ ((krow & 7) << 3)), ksB + e);
        const int vrow = e >> 6;
        gll16(vpl + (size_t)vrow * S_ + t1 + ((e & 63) ^ ((vrow & 7) << 3)), vtB + e);
      }
    }

    // QK^T swapped: sa[nt][r] = S[t = t0+nt*16+lh*4+r][q = qrow]
    f32x4 sa[4] = {};
    __builtin_amdgcn_s_setprio(1);
#pragma unroll
    for (int nt = 0; nt < 4; ++nt)
#pragma unroll
      for (int kk = 0; kk < 4; ++kk) {
        const int row = nt * 16 + lr;
        f16x8 kb = *(const f16x8*)(ksA + row * D_ + ((kk * 32 + lh * 8) ^ swz));
        sa[nt] = MFMA16(kb, qa[kk], sa[nt]);
      }
    __builtin_amdgcn_s_setprio(0);

    // epilogue: score = (qk+pb)/sqrtD + mask + prev ; pure VALU + store
#pragma unroll
    for (int nt = 0; nt < 4; ++nt) {
      const int toff = t0 + nt * 16 + lh * 4;
      f32x4 sc4 = (sa[nt] + pb4[nt]) * RSQRT_D + mk4[nt] + pv4[nt];
      __builtin_nontemporal_store(sc4, (f32x4*)(srow + toff));
      sa[nt] = sc4;
    }

    // online softmax, one q-row per lane; row group = lanes {l, l^16, l^32, l^48}
    float tmx = -1e30f;
#pragma unroll
    for (int nt = 0; nt < 4; ++nt)
#pragma unroll
      for (int r = 0; r < 4; ++r) tmx = fmaxf(tmx, sa[nt][r]);
    tmx = fmaxf(tmx, __shfl_xor(tmx, 16));
    tmx = fmaxf(tmx, __shfl_xor(tmx, 32));
    if (!__all(tmx <= m_r + 8.0f)) {   // T13 defer-max
      const float newm = fmaxf(m_r, tmx);
      const float al = __expf(m_r - newm);
      m_r = newm;
      l_r *= al;
#pragma unroll
      for (int nd = 0; nd < 8; ++nd) o[nd] *= al;
    }
    float ts = 0.0f;
#pragma unroll
    for (int nt = 0; nt < 4; ++nt)
#pragma unroll
      for (int r = 0; r < 4; ++r) {
        const float pe = __expf(sa[nt][r] - m_r);
        sa[nt][r] = pe;
        ts += pe;
      }
    ts += __shfl_xor(ts, 16);
    ts += __shfl_xor(ts, 32);
    l_r += ts;

    // P -> per-wave LDS [q=lr][t], swizzled, f16x4 stores (wave-local)
    _Float16* pw = &Ps[w][0];
#pragma unroll
    for (int nt = 0; nt < 4; ++nt) {
      f16x4 pk;
      pk[0] = (_Float16)sa[nt][0]; pk[1] = (_Float16)sa[nt][1];
      pk[2] = (_Float16)sa[nt][2]; pk[3] = (_Float16)sa[nt][3];
      *(f16x4*)(pw + lr * BT + ((nt * 16 + lh * 4) ^ swz)) = pk;
    }

    // PV swapped: o[nd][r] = ctx[d = nd*16+lh*4+r][q = qrow]
    __builtin_amdgcn_s_setprio(1);
#pragma unroll
    for (int kk2 = 0; kk2 < 2; ++kk2) {
      const f16x8 pa = *(const f16x8*)(pw + lr * BT + ((kk2 * 32 + lh * 8) ^ swz));
#pragma unroll
      for (int nd = 0; nd < 8; ++nd) {
        const int vr = nd * 16 + lr;
        const f16x8 vb = *(const f16x8*)(vtA + vr * BT + ((kk2 * 32 + lh * 8) ^ swz));
        o[nd] = MFMA16(vb, pa, o[nd]);
      }
    }
    __builtin_amdgcn_s_setprio(0);

    // sole drain point: waits this wave's gll16s + stores, then barrier
    __syncthreads();
    _Float16* t1p = ksA; ksA = ksB; ksB = t1p;
    _Float16* t2p = vtA; vtA = vtB; vtB = t2p;
  }

  // ctx write: lane owns q-row qrow, d = nd*16 + lh*4 + r -> f16x4 stores
  const float inv_l = 1.0f / l_r;
  _Float16* crow = ctx + ((size_t)(b * S_) + qrow) * HID_ + h * D_;
#pragma unroll
  for (int nd = 0; nd < 8; ++nd) {
    f16x4 cv;
#pragma unroll
    for (int r = 0; r < 4; ++r) cv[r] = (_Float16)(o[nd][r] * inv_l);
    *(f16x4*)(crow + nd * 16 + lh * 4) = cv;
  }
}

// ---------------------------------------------------------------------------
extern "C" void kernel_launch(void* const* d_in, const int* in_sizes, int n_in,
                              void* d_out, int out_size, void* d_ws, size_t ws_size,
                              hipStream_t stream) {
  const float* query = (const float*)d_in[0];
  const float* key_i = (const float*)d_in[1];
  const float* value = (const float*)d_in[2];
  const float* maskp = (const float*)d_in[3];
  const float* pbias = (const float*)d_in[4];
  const float* prev  = (const float*)d_in[5];
  const int*   pids  = (const int*)d_in[6];
  const float* Wq = (const float*)d_in[7];
  const float* bq = (const float*)d_in[8];
  const float* Wk = (const float*)d_in[9];
  const float* bk = (const float*)d_in[10];
  const float* Wv = (const float*)d_in[11];
  const float* bv = (const float*)d_in[12];
  const float* Wo = (const float*)d_in[13];
  const float* bo = (const float*)d_in[14];

  char* ws = (char*)d_ws;
  // workspace layout (bytes); total need = 134,479,872
  const size_t OFF_TCOS = 0;
  const size_t OFF_TSIN = 131072;
  const size_t OFF_W    = 262144;                      // 4 x 8 MB f16 weights
  const size_t OFF_X    = OFF_W + 4ull * 8388608;      // 3 x 16 MB f16 X
  const size_t OFF_Q    = OFF_X + 3ull * 16777216;
  const size_t OFF_K    = OFF_Q + 16777216;
  const size_t OFF_VT   = OFF_K + 16777216;            // V proj writes here (B,H,D,S)
  const size_t OFF_CTX  = OFF_X + 16777216;            // reuse Xk (consumed)

  float* tcos = (float*)(ws + OFF_TCOS);
  float* tsin = (float*)(ws + OFF_TSIN);
  _Float16* Wq16 = (_Float16*)(ws + OFF_W);
  _Float16* Wk16 = (_Float16*)(ws + OFF_W + 8388608);
  _Float16* Wv16 = (_Float16*)(ws + OFF_W + 2ull * 8388608);
  _Float16* Wo16 = (_Float16*)(ws + OFF_W + 3ull * 8388608);
  _Float16* Xq16 = (_Float16*)(ws + OFF_X);
  _Float16* Xk16 = (_Float16*)(ws + OFF_X + 16777216);
  _Float16* Xv16 = (_Float16*)(ws + OFF_X + 2ull * 16777216);
  _Float16* q16  = (_Float16*)(ws + OFF_Q);
  _Float16* k16  = (_Float16*)(ws + OFF_K);
  _Float16* vt16 = (_Float16*)(ws + OFF_VT);
  _Float16* ctx16 = (_Float16*)(ws + OFF_CTX);

  float* out_f32 = (float*)d_out;                 // (B,S,HID) = 8,388,608
  float* scores  = (float*)d_out + 8388608;       // (B,H,S,S) = 67,108,864

  // one merged convert + RoPE tables (20480 cvt blocks + 128 table blocks)
  cvt_all_kernel<<<20608, 256, 0, stream>>>(Wq, Wk, Wv, Wo, query, key_i, value,
                                            Wq16, Wk16, Wv16, Wo16,
                                            Xq16, Xk16, Xv16, tcos, tsin);

  // fused Q/K/V projections (3 x 512 blocks, one launch)
  proj_qkv_kernel<<<1536, 256, 0, stream>>>(Xq16, Xk16, Xv16,
                                            Wq16, Wk16, Wv16,
                                            bq, bk, bv,
                                            q16, k16, vt16,
                                            pids, tcos, tsin);

  flash_kernel<<<1024, 256, 0, stream>>>(q16, k16, vt16, pbias, maskp, prev,
                                         scores, ctx16);

  proj_out_kernel<<<512, 256, 0, stream>>>(ctx16, Wo16, bo, out_f32);
}

// Round 14
// 445.263 us; speedup vs baseline: 1.1256x; 1.0224x over previous
//
#include <hip/hip_runtime.h>

// ---------------------------------------------------------------------------
// GLMAttention: qkv proj (+RoPE) -> fused flash attn (scores out + softmax+PV)
// -> output proj.  All matmuls fp16 MFMA (16x16x32), f32 accumulate.
// B=4 S=1024 HID=2048 H=16 D=128.
// Round 14: flash loop-end barrier = raw s_barrier + counted vmcnt(4):
// retires the 8 gll16 staging ops (the only cross-wave dep) but leaves the
// 4 nontemporal scores stores in flight -- the full-drain __syncthreads was
// making every wave wait on HBM write-acks each iteration.
// ---------------------------------------------------------------------------

#define B_  4
#define S_  1024
#define HID_ 2048
#define H_  16
#define D_  128
#define RSQRT_D 0.08838834764831845f

typedef _Float16 f16x8 __attribute__((ext_vector_type(8)));
typedef _Float16 f16x4 __attribute__((ext_vector_type(4)));
typedef float f32x4 __attribute__((ext_vector_type(4)));

#define MFMA16(a, b, c) __builtin_amdgcn_mfma_f32_16x16x32_f16(a, b, c, 0, 0, 0)

__device__ __forceinline__ void gll16(const void* g, void* l) {
  __builtin_amdgcn_global_load_lds(
      (const __attribute__((address_space(1))) void*)g,
      (__attribute__((address_space(3))) void*)l, 16, 0, 0);
}

// ---------------------------------------------------------------------------
// Merged f32 -> f16 convert for all 7 tensors + RoPE tables.
// Blocks [0, 20480): convert (8 elems/thread). Blocks [20480, 20608): tables.
// ---------------------------------------------------------------------------
__global__ __launch_bounds__(256) void cvt_all_kernel(
    const float* __restrict__ w0, const float* __restrict__ w1,
    const float* __restrict__ w2, const float* __restrict__ w3,
    const float* __restrict__ x0, const float* __restrict__ x1,
    const float* __restrict__ x2,
    _Float16* __restrict__ dw0, _Float16* __restrict__ dw1,
    _Float16* __restrict__ dw2, _Float16* __restrict__ dw3,
    _Float16* __restrict__ dx0, _Float16* __restrict__ dx1,
    _Float16* __restrict__ dx2,
    float* __restrict__ tcos, float* __restrict__ tsin) {
  if (blockIdx.x >= 20480) {  // RoPE tables: 32768 entries
    const int i = (blockIdx.x - 20480) * 256 + threadIdx.x;
    const int pos = i >> 5, j = i & 31;
    const float inv = expf(-(float)j * (9.210340371976184f / 32.0f));
    const float ang = (float)pos * inv;
    tcos[i] = cosf(ang);
    tsin[i] = sinf(ang);
    return;
  }
  const int i = blockIdx.x * blockDim.x + threadIdx.x;  // unit index
  const float* src;
  _Float16* dst;
  int off;
  if (i < 2097152) {                 // weights: 4 x 524288
    const int seg = i >> 19;
    off = i & 524287;
    src = (seg == 0) ? w0 : (seg == 1) ? w1 : (seg == 2) ? w2 : w3;
    dst = (seg == 0) ? dw0 : (seg == 1) ? dw1 : (seg == 2) ? dw2 : dw3;
  } else {                           // X: 3 x 1048576
    const int j = i - 2097152;
    const int seg = j >> 20;
    off = j & 1048575;
    src = (seg == 0) ? x0 : (seg == 1) ? x1 : x2;
    dst = (seg == 0) ? dx0 : (seg == 1) ? dx1 : dx2;
  }
  const f32x4* in4 = (const f32x4*)src;
  f32x4 a = in4[(size_t)off * 2], b = in4[(size_t)off * 2 + 1];
  f16x8 v;
  v[0] = (_Float16)a[0]; v[1] = (_Float16)a[1]; v[2] = (_Float16)a[2]; v[3] = (_Float16)a[3];
  v[4] = (_Float16)b[0]; v[5] = (_Float16)b[1]; v[6] = (_Float16)b[2]; v[7] = (_Float16)b[3];
  *(f16x8*)(dst + (size_t)off * 8) = v;
}

// ---------------------------------------------------------------------------
// Fused Q/K/V projection: one 1536-block launch, 512 blocks per segment.
// C = A(MxK) @ W(NxK)^T + bias; seg 0/1 -> RoPE epilogue (B,H,S,D);
// seg 2 (V) -> transposed head epilogue (B,H,D,S).
// 128x128 tile, BK=64, 4 waves, 4x4 frags; global XCD swizzle (1536%8==0).
// ---------------------------------------------------------------------------
__global__ __launch_bounds__(256) void proj_qkv_kernel(
    const _Float16* __restrict__ Xq, const _Float16* __restrict__ Xk,
    const _Float16* __restrict__ Xv,
    const _Float16* __restrict__ Wq, const _Float16* __restrict__ Wk,
    const _Float16* __restrict__ Wv,
    const float* __restrict__ bq, const float* __restrict__ bk,
    const float* __restrict__ bv,
    _Float16* __restrict__ oq, _Float16* __restrict__ ok,
    _Float16* __restrict__ ovt,
    const int* __restrict__ pids, const float* __restrict__ tcos,
    const float* __restrict__ tsin) {
  constexpr int N = HID_, K = HID_;
  constexpr int BK = 64;
  __shared__ _Float16 As[128 * BK];
  __shared__ _Float16 Bs[128 * BK];

  const int tid = threadIdx.x;
  // XCD-aware swizzle over the full 1536-block grid (1536%8==0 -> bijective)
  const int gbid = (blockIdx.x & 7) * 192 + (blockIdx.x >> 3);
  const int seg = gbid >> 9;          // 0=q, 1=k, 2=v (block-uniform)
  const int bid = gbid & 511;
  const _Float16* A  = (seg == 0) ? Xq : (seg == 1) ? Xk : Xv;
  const _Float16* Bw = (seg == 0) ? Wq : (seg == 1) ? Wk : Wv;
  const float*  bias = (seg == 0) ? bq : (seg == 1) ? bk : bv;

  const int tm = bid >> 4, tn = bid & 15;  // 32 x 16 tiles
  const int m0 = tm * 128, n0 = tn * 128;
  const int w = tid >> 6, l = tid & 63;
  const int mw = (w >> 1) * 64, nw = (w & 1) * 64;
  const int lr = l & 15, lh = l >> 4;

  f32x4 acc[4][4] = {};

  for (int kt = 0; kt < K / BK; ++kt) {
    const int k0 = kt * BK;
    __syncthreads();
#pragma unroll
    for (int i = 0; i < 4; ++i) {
      const int e = i * 2048 + tid * 8;
      gll16(A + (size_t)(m0 + (e >> 6)) * K + k0 + (e & 63), As + e);
      gll16(Bw + (size_t)(n0 + (e >> 6)) * K + k0 + (e & 63), Bs + e);
    }
    asm volatile("s_waitcnt vmcnt(0)" ::: "memory");
    __syncthreads();
#pragma unroll
    for (int kk = 0; kk < 2; ++kk) {
      f16x8 af[4], bf[4];
#pragma unroll
      for (int mi = 0; mi < 4; ++mi)
        af[mi] = *(const f16x8*)(As + (mw + mi * 16 + lr) * BK + kk * 32 + lh * 8);
#pragma unroll
      for (int ni = 0; ni < 4; ++ni)
        bf[ni] = *(const f16x8*)(Bs + (nw + ni * 16 + lr) * BK + kk * 32 + lh * 8);
#pragma unroll
      for (int mi = 0; mi < 4; ++mi)
#pragma unroll
        for (int ni = 0; ni < 4; ++ni)
          acc[mi][ni] = MFMA16(af[mi], bf[ni], acc[mi][ni]);
    }
  }

  if (seg == 2) {  // V: write (B,H,D,S) directly
    _Float16* out = ovt;
#pragma unroll
    for (int mi = 0; mi < 4; ++mi)
#pragma unroll
      for (int ni = 0; ni < 4; ++ni) {
        const int col = n0 + nw + ni * 16 + lr;
        const float bb = bias[col];
        const int h = col >> 7, hd = col & 127;
#pragma unroll
        for (int r = 0; r < 4; ++r) {
          const int row = m0 + mw + mi * 16 + lh * 4 + r;
          const int b = row >> 10, s = row & 1023;
          out[(((size_t)(b * H_ + h)) * D_ + hd) * S_ + s] = (_Float16)(acc[mi][ni][r] + bb);
        }
      }
  } else {  // q/k: RoPE epilogue. wave covers cols = head dims [0,64) or [64,128)
    _Float16* out = (seg == 0) ? oq : ok;
    const int sel = (nw >> 6) & 1;  // 0 -> pid row, 1 -> bid row of position_ids
#pragma unroll
    for (int mi = 0; mi < 4; ++mi) {
#pragma unroll
      for (int r = 0; r < 4; ++r) {
        const int row = m0 + mw + mi * 16 + lh * 4 + r;
        const int b = row >> 10, s = row & 1023;
        const int pos = pids[b * 2 * S_ + sel * S_ + s];
#pragma unroll
        for (int ni = 0; ni < 2; ++ni) {
          const int col = n0 + nw + ni * 16 + lr;  // first of (d, d+32) pair
          const int j = ni * 16 + lr;              // 0..31 freq index
          const float c = tcos[pos * 32 + j];
          const float sn = tsin[pos * 32 + j];
          const float x1 = acc[mi][ni][r] + bias[col];
          const float x2 = acc[mi][ni + 2][r] + bias[col + 32];
          const int h = col >> 7, hd = col & 127;
          const size_t base = (((size_t)(b * H_ + h)) * S_ + s) * D_;
          out[base + hd] = (_Float16)(x1 * c - x2 * sn);
          out[base + hd + 32] = (_Float16)(x2 * c + x1 * sn);
        }
      }
    }
  }
}

// ---------------------------------------------------------------------------
// Final projection: C = ctx @ Wo^T + bo -> f32 (M,N).
// ---------------------------------------------------------------------------
__global__ __launch_bounds__(256) void proj_out_kernel(
    const _Float16* __restrict__ A, const _Float16* __restrict__ Bw,
    const float* __restrict__ bias, float* __restrict__ out) {
  constexpr int N = HID_, K = HID_;
  constexpr int BK = 64;
  __shared__ _Float16 As[128 * BK];
  __shared__ _Float16 Bs[128 * BK];

  const int tid = threadIdx.x;
  const int bid = (blockIdx.x & 7) * 64 + (blockIdx.x >> 3);
  const int tm = bid >> 4, tn = bid & 15;
  const int m0 = tm * 128, n0 = tn * 128;
  const int w = tid >> 6, l = tid & 63;
  const int mw = (w >> 1) * 64, nw = (w & 1) * 64;
  const int lr = l & 15, lh = l >> 4;

  f32x4 acc[4][4] = {};

  for (int kt = 0; kt < K / BK; ++kt) {
    const int k0 = kt * BK;
    __syncthreads();
#pragma unroll
    for (int i = 0; i < 4; ++i) {
      const int e = i * 2048 + tid * 8;
      gll16(A + (size_t)(m0 + (e >> 6)) * K + k0 + (e & 63), As + e);
      gll16(Bw + (size_t)(n0 + (e >> 6)) * K + k0 + (e & 63), Bs + e);
    }
    asm volatile("s_waitcnt vmcnt(0)" ::: "memory");
    __syncthreads();
#pragma unroll
    for (int kk = 0; kk < 2; ++kk) {
      f16x8 af[4], bf[4];
#pragma unroll
      for (int mi = 0; mi < 4; ++mi)
        af[mi] = *(const f16x8*)(As + (mw + mi * 16 + lr) * BK + kk * 32 + lh * 8);
#pragma unroll
      for (int ni = 0; ni < 4; ++ni)
        bf[ni] = *(const f16x8*)(Bs + (nw + ni * 16 + lr) * BK + kk * 32 + lh * 8);
#pragma unroll
      for (int mi = 0; mi < 4; ++mi)
#pragma unroll
        for (int ni = 0; ni < 4; ++ni)
          acc[mi][ni] = MFMA16(af[mi], bf[ni], acc[mi][ni]);
    }
  }

#pragma unroll
  for (int mi = 0; mi < 4; ++mi)
#pragma unroll
    for (int ni = 0; ni < 4; ++ni) {
      const int col = n0 + nw + ni * 16 + lr;
      const float bb = bias[col];
#pragma unroll
      for (int r = 0; r < 4; ++r) {
        const int row = m0 + mw + mi * 16 + lh * 4 + r;
        out[(size_t)row * N + col] = acc[mi][ni][r] + bb;
      }
    }
}

// ---------------------------------------------------------------------------
// Fused flash attention, 2-phase double-buffered.
// Block = (b,h, 64 q-rows); 4 waves x 16 rows. Swapped MFMA operands
// (S layout [t][q], o layout [d][q]); LDS XOR-swizzled via pre-swizzled
// global_load_lds source. Loop-end barrier: raw s_barrier + vmcnt(4) --
// retires gll16 staging, leaves the 4 scores stores in flight.
// ---------------------------------------------------------------------------
__global__ __launch_bounds__(256) void flash_kernel(
    const _Float16* __restrict__ q, const _Float16* __restrict__ k,
    const _Float16* __restrict__ vt, const float* __restrict__ pbias,
    const float* __restrict__ maskp, const float* __restrict__ prev,
    float* __restrict__ scores, _Float16* __restrict__ ctx) {
  constexpr int BT = 64;
  __shared__ _Float16 KsBuf[2][BT * D_];   // [t][d] swizzled, 2 x 16 KB
  __shared__ _Float16 VTsBuf[2][D_ * BT];  // [d][t] swizzled, 2 x 16 KB
  __shared__ _Float16 Ps[4][16 * BT];      // per-wave [q][t] swizzled, 8 KB

  const int tid = threadIdx.x, w = tid >> 6, l = tid & 63;
  const int lr = l & 15, lh = l >> 4;
  // XCD swizzle: 1024 blocks -> 128 consecutive per XCD (8 planes/XCD)
  const int sid = (blockIdx.x & 7) * 128 + (blockIdx.x >> 3);
  const int qt = sid & 15, byh = sid >> 4;
  const int b = byh >> 4, h = byh & 15;
  const size_t plane = (size_t)byh;
  const int q0 = qt * 64 + w * 16;
  const int qrow = q0 + lr;           // this lane's q-row
  const int swz = (lr & 7) << 3;      // element-index XOR for frag reads

  const float* prow  = prev  + (plane * S_ + qrow) * S_;
  const float* pbrow = pbias + ((size_t)h * S_ + qrow) * S_;
  const float* mrow  = maskp + ((size_t)b * S_ + qrow) * S_;
  float*       srow  = scores + (plane * S_ + qrow) * S_;
  const _Float16* kpl = k  + plane * S_ * D_;
  const _Float16* vpl = vt + plane * D_ * S_;

  // Q B-fragments: lane provides Q[row=lr][k]
  f16x8 qa[4];
#pragma unroll
  for (int kk = 0; kk < 4; ++kk)
    qa[kk] = *(const f16x8*)(q + (plane * S_ + qrow) * D_ + kk * 32 + lh * 8);

  f32x4 o[8] = {};
  float m_r = -1e30f, l_r = 0.0f;

  _Float16* ksA = &KsBuf[0][0];
  _Float16* ksB = &KsBuf[1][0];
  _Float16* vtA = &VTsBuf[0][0];
  _Float16* vtB = &VTsBuf[1][0];

  // prologue: stage tile 0 into buffer A
#pragma unroll
  for (int i = 0; i < 4; ++i) {
    const int e = i * 2048 + tid * 8;
    const int krow = e >> 7;
    gll16(kpl + (size_t)krow * D_ + ((e & 127) ^ ((krow & 7) << 3)), ksA + e);
    const int vrow = e >> 6;
    gll16(vpl + (size_t)vrow * S_ + ((e & 63) ^ ((vrow & 7) << 3)), vtA + e);
  }
  __syncthreads();   // full drain once at prologue

  for (int tt = 0; tt < S_ / BT; ++tt) {
    const int t0 = tt * BT;

    // streams for THIS tile (needed after QK^T; deepest-issued)
    f32x4 pv4[4], pb4[4], mk4[4];
#pragma unroll
    for (int nt = 0; nt < 4; ++nt) {
      const int toff = t0 + nt * 16 + lh * 4;
      pv4[nt] = __builtin_nontemporal_load((const f32x4*)(prow + toff));
      pb4[nt] = *(const f32x4*)(pbrow + toff);
      mk4[nt] = *(const f32x4*)(mrow + toff);
    }
    // STAGE next tile into the other buffer (async DMA; retired at the
    // loop-end counted-vmcnt barrier)
    if (tt < S_ / BT - 1) {
      const int t1 = t0 + BT;
#pragma unroll
      for (int i = 0; i < 4; ++i) {
        const int e = i * 2048 + tid * 8;
        const int krow = e >> 7;
        gll16(kpl + (size_t)(t1 + krow) * D_ + ((e & 127) ^ ((krow & 7) << 3)), ksB + e);
        const int vrow = e >> 6;
        gll16(vpl + (size_t)vrow * S_ + t1 + ((e & 63) ^ ((vrow & 7) << 3)), vtB + e);
      }
    }

    // QK^T swapped: sa[nt][r] = S[t = t0+nt*16+lh*4+r][q = qrow]
    f32x4 sa[4] = {};
    __builtin_amdgcn_s_setprio(1);
#pragma unroll
    for (int nt = 0; nt < 4; ++nt)
#pragma unroll
      for (int kk = 0; kk < 4; ++kk) {
        const int row = nt * 16 + lr;
        f16x8 kb = *(const f16x8*)(ksA + row * D_ + ((kk * 32 + lh * 8) ^ swz));
        sa[nt] = MFMA16(kb, qa[kk], sa[nt]);
      }
    __builtin_amdgcn_s_setprio(0);

    // epilogue: score = (qk+pb)/sqrtD + mask + prev ; pure VALU + store
#pragma unroll
    for (int nt = 0; nt < 4; ++nt) {
      const int toff = t0 + nt * 16 + lh * 4;
      f32x4 sc4 = (sa[nt] + pb4[nt]) * RSQRT_D + mk4[nt] + pv4[nt];
      __builtin_nontemporal_store(sc4, (f32x4*)(srow + toff));
      sa[nt] = sc4;
    }

    // online softmax, one q-row per lane; row group = lanes {l, l^16, l^32, l^48}
    float tmx = -1e30f;
#pragma unroll
    for (int nt = 0; nt < 4; ++nt)
#pragma unroll
      for (int r = 0; r < 4; ++r) tmx = fmaxf(tmx, sa[nt][r]);
    tmx = fmaxf(tmx, __shfl_xor(tmx, 16));
    tmx = fmaxf(tmx, __shfl_xor(tmx, 32));
    if (!__all(tmx <= m_r + 8.0f)) {   // T13 defer-max
      const float newm = fmaxf(m_r, tmx);
      const float al = __expf(m_r - newm);
      m_r = newm;
      l_r *= al;
#pragma unroll
      for (int nd = 0; nd < 8; ++nd) o[nd] *= al;
    }
    float ts = 0.0f;
#pragma unroll
    for (int nt = 0; nt < 4; ++nt)
#pragma unroll
      for (int r = 0; r < 4; ++r) {
        const float pe = __expf(sa[nt][r] - m_r);
        sa[nt][r] = pe;
        ts += pe;
      }
    ts += __shfl_xor(ts, 16);
    ts += __shfl_xor(ts, 32);
    l_r += ts;

    // P -> per-wave LDS [q=lr][t], swizzled, f16x4 stores (wave-local)
    _Float16* pw = &Ps[w][0];
#pragma unroll
    for (int nt = 0; nt < 4; ++nt) {
      f16x4 pk;
      pk[0] = (_Float16)sa[nt][0]; pk[1] = (_Float16)sa[nt][1];
      pk[2] = (_Float16)sa[nt][2]; pk[3] = (_Float16)sa[nt][3];
      *(f16x4*)(pw + lr * BT + ((nt * 16 + lh * 4) ^ swz)) = pk;
    }

    // PV swapped: o[nd][r] = ctx[d = nd*16+lh*4+r][q = qrow]
    __builtin_amdgcn_s_setprio(1);
#pragma unroll
    for (int kk2 = 0; kk2 < 2; ++kk2) {
      const f16x8 pa = *(const f16x8*)(pw + lr * BT + ((kk2 * 32 + lh * 8) ^ swz));
#pragma unroll
      for (int nd = 0; nd < 8; ++nd) {
        const int vr = nd * 16 + lr;
        const f16x8 vb = *(const f16x8*)(vtA + vr * BT + ((kk2 * 32 + lh * 8) ^ swz));
        o[nd] = MFMA16(vb, pa, o[nd]);
      }
    }
    __builtin_amdgcn_s_setprio(0);

    // loop-end barrier: retire gll16 staging (cross-wave dep) but leave the
    // 4 scores stores (newest outstanding VM ops) in flight.
    asm volatile("s_waitcnt vmcnt(4)" ::: "memory");
    __builtin_amdgcn_s_barrier();
    _Float16* t1p = ksA; ksA = ksB; ksB = t1p;
    _Float16* t2p = vtA; vtA = vtB; vtB = t2p;
  }

  // ctx write: lane owns q-row qrow, d = nd*16 + lh*4 + r -> f16x4 stores
  const float inv_l = 1.0f / l_r;
  _Float16* crow = ctx + ((size_t)(b * S_) + qrow) * HID_ + h * D_;
#pragma unroll
  for (int nd = 0; nd < 8; ++nd) {
    f16x4 cv;
#pragma unroll
    for (int r = 0; r < 4; ++r) cv[r] = (_Float16)(o[nd][r] * inv_l);
    *(f16x4*)(crow + nd * 16 + lh * 4) = cv;
  }
}

// ---------------------------------------------------------------------------
extern "C" void kernel_launch(void* const* d_in, const int* in_sizes, int n_in,
                              void* d_out, int out_size, void* d_ws, size_t ws_size,
                              hipStream_t stream) {
  const float* query = (const float*)d_in[0];
  const float* key_i = (const float*)d_in[1];
  const float* value = (const float*)d_in[2];
  const float* maskp = (const float*)d_in[3];
  const float* pbias = (const float*)d_in[4];
  const float* prev  = (const float*)d_in[5];
  const int*   pids  = (const int*)d_in[6];
  const float* Wq = (const float*)d_in[7];
  const float* bq = (const float*)d_in[8];
  const float* Wk = (const float*)d_in[9];
  const float* bk = (const float*)d_in[10];
  const float* Wv = (const float*)d_in[11];
  const float* bv = (const float*)d_in[12];
  const float* Wo = (const float*)d_in[13];
  const float* bo = (const float*)d_in[14];

  char* ws = (char*)d_ws;
  // workspace layout (bytes); total need = 134,479,872
  const size_t OFF_TCOS = 0;
  const size_t OFF_TSIN = 131072;
  const size_t OFF_W    = 262144;                      // 4 x 8 MB f16 weights
  const size_t OFF_X    = OFF_W + 4ull * 8388608;      // 3 x 16 MB f16 X
  const size_t OFF_Q    = OFF_X + 3ull * 16777216;
  const size_t OFF_K    = OFF_Q + 16777216;
  const size_t OFF_VT   = OFF_K + 16777216;            // V proj writes here (B,H,D,S)
  const size_t OFF_CTX  = OFF_X + 16777216;            // reuse Xk (consumed)

  float* tcos = (float*)(ws + OFF_TCOS);
  float* tsin = (float*)(ws + OFF_TSIN);
  _Float16* Wq16 = (_Float16*)(ws + OFF_W);
  _Float16* Wk16 = (_Float16*)(ws + OFF_W + 8388608);
  _Float16* Wv16 = (_Float16*)(ws + OFF_W + 2ull * 8388608);
  _Float16* Wo16 = (_Float16*)(ws + OFF_W + 3ull * 8388608);
  _Float16* Xq16 = (_Float16*)(ws + OFF_X);
  _Float16* Xk16 = (_Float16*)(ws + OFF_X + 16777216);
  _Float16* Xv16 = (_Float16*)(ws + OFF_X + 2ull * 16777216);
  _Float16* q16  = (_Float16*)(ws + OFF_Q);
  _Float16* k16  = (_Float16*)(ws + OFF_K);
  _Float16* vt16 = (_Float16*)(ws + OFF_VT);
  _Float16* ctx16 = (_Float16*)(ws + OFF_CTX);

  float* out_f32 = (float*)d_out;                 // (B,S,HID) = 8,388,608
  float* scores  = (float*)d_out + 8388608;       // (B,H,S,S) = 67,108,864

  // one merged convert + RoPE tables (20480 cvt blocks + 128 table blocks)
  cvt_all_kernel<<<20608, 256, 0, stream>>>(Wq, Wk, Wv, Wo, query, key_i, value,
                                            Wq16, Wk16, Wv16, Wo16,
                                            Xq16, Xk16, Xv16, tcos, tsin);

  // fused Q/K/V projections (3 x 512 blocks, one launch)
  proj_qkv_kernel<<<1536, 256, 0, stream>>>(Xq16, Xk16, Xv16,
                                            Wq16, Wk16, Wv16,
                                            bq, bk, bv,
                                            q16, k16, vt16,
                                            pids, tcos, tsin);

  flash_kernel<<<1024, 256, 0, stream>>>(q16, k16, vt16, pbias, maskp, prev,
                                         scores, ctx16);

  proj_out_kernel<<<512, 256, 0, stream>>>(ctx16, Wo16, bo, out_f32);
}